// Round 1
// baseline (597.252 us; speedup 1.0000x reference)
//
#include <hip/hip_runtime.h>
#include <stdint.h>

#define TSEQ 2048
#define NHEAD 16

typedef __attribute__((ext_vector_type(8))) short bf16x8;
typedef __attribute__((ext_vector_type(4))) float f32x4;

__device__ __forceinline__ unsigned short f2bf(float f) {
  union { float f; uint32_t u; } c;
  c.f = f;
  uint32_t u = c.u;
  u += 0x7fffu + ((u >> 16) & 1u);   // round-nearest-even
  return (unsigned short)(u >> 16);
}

using as3_void  = __attribute__((address_space(3))) void;
using as1_cvoid = const __attribute__((address_space(1))) void;

__device__ __forceinline__ void gld_lds16(const void* g, void* l) {
  // async global->LDS, 16B per lane; LDS dest = wave-uniform base + lane*16
  __builtin_amdgcn_global_load_lds((as1_cvoid*)g, (as3_void*)l, 16, 0, 0);
}

// ---------------- prep kernels ----------------

__global__ void cast_x_kernel(const float4* __restrict__ x, ushort4* __restrict__ xb) {
  int i = blockIdx.x * 256 + threadIdx.x;
  float4 v = x[i];
  ushort4 o;
  o.x = f2bf(v.x); o.y = f2bf(v.y); o.z = f2bf(v.z); o.w = f2bf(v.w);
  xb[i] = o;
}

// Wq/Wk/Wv [H,C,HD] f32 -> BT [(which*1024 + h*64 + d)][c] bf16
__global__ void repack_wqkv(const float* __restrict__ Wq, const float* __restrict__ Wk,
                            const float* __restrict__ Wv, unsigned short* __restrict__ BT) {
  __shared__ unsigned short tile[64][72];
  const float* W = (blockIdx.z == 0) ? Wq : (blockIdx.z == 1) ? Wk : Wv;
  const int h = blockIdx.y;
  const int c0 = blockIdx.x * 64;
  const int t = threadIdx.x;
  const float* src = W + ((size_t)h * 1024 + c0) * 64;
#pragma unroll
  for (int p = 0; p < 16; ++p) {
    int idx = p * 256 + t;
    int cc = idx >> 6, d = idx & 63;
    tile[cc][d] = f2bf(src[(size_t)cc * 64 + d]);
  }
  __syncthreads();
  unsigned short* dst = BT + ((size_t)blockIdx.z * 1024 + (size_t)h * 64) * 1024 + c0;
#pragma unroll
  for (int p = 0; p < 16; ++p) {
    int idx = p * 256 + t;
    int d = idx >> 6, cc = idx & 63;
    dst[(size_t)d * 1024 + cc] = tile[cc][d];
  }
}

// Wo [C,C] f32 -> WoT [n][k] bf16 (transpose)
__global__ void repack_wo(const float* __restrict__ Wo, unsigned short* __restrict__ WoT) {
  __shared__ unsigned short tile[64][72];
  const int k0 = blockIdx.x * 64;
  const int n0 = blockIdx.y * 64;
  const int t = threadIdx.x;
#pragma unroll
  for (int p = 0; p < 16; ++p) {
    int idx = p * 256 + t;
    int kk = idx >> 6, nn = idx & 63;
    tile[kk][nn] = f2bf(Wo[(size_t)(k0 + kk) * 1024 + n0 + nn]);
  }
  __syncthreads();
#pragma unroll
  for (int p = 0; p < 16; ++p) {
    int idx = p * 256 + t;
    int nn = idx >> 6, kk = idx & 63;
    WoT[(size_t)(n0 + nn) * 1024 + k0 + kk] = tile[kk][nn];
  }
}

// ---------------- GEMM: C = A[M,K] * BT[N,K]^T + bias ----------------
// 128x128 tile, BK=64, 256 thr = 4 waves (2x2), 4x4 16x16x32 frags/wave.
// MODE 0: QKV epilogue (scatter to q [BH,T,64], k [BH,T,64], vT [BH,64,T], bf16)
// MODE 1: f32 output + bias

template <int MODE>
__global__ __launch_bounds__(256) void gemm_bt(
    const unsigned short* __restrict__ A, const unsigned short* __restrict__ BTm,
    const float* __restrict__ bias0, const float* __restrict__ bias1,
    const float* __restrict__ bias2,
    unsigned short* __restrict__ qo, unsigned short* __restrict__ ko,
    unsigned short* __restrict__ vto, float* __restrict__ outf,
    int M, int N, int K) {
  __shared__ unsigned short As[128 * 64];
  __shared__ unsigned short Bs[128 * 64];
  const int tid = threadIdx.x;
  const int lane = tid & 63;
  const int wv = tid >> 6;
  const int wr = wv >> 1, wc = wv & 1;
  const int g = lane >> 4, r = lane & 15;
  const int m0 = blockIdx.x * 128;
  const int n0 = blockIdx.y * 128;

  f32x4 acc[4][4] = {};

  const int arow = tid >> 3;            // 0..31
  const int acol = (tid & 7) * 8;       // 0..56
  const unsigned short* Ab = A + (size_t)(m0 + arow) * K + acol;
  const unsigned short* Bb = BTm + (size_t)(n0 + arow) * K + acol;
  char* AsB = (char*)As + wv * 1024;
  char* BsB = (char*)Bs + wv * 1024;

  for (int k0 = 0; k0 < K; k0 += 64) {
#pragma unroll
    for (int i = 0; i < 4; ++i) {
      gld_lds16(Ab + (size_t)i * 32 * K + k0, AsB + i * 4096);
      gld_lds16(Bb + (size_t)i * 32 * K + k0, BsB + i * 4096);
    }
    __syncthreads();   // drains vmcnt(0) before barrier (compiler-emitted)
    const char* Ar = (const char*)As;
    const char* Br = (const char*)Bs;
#pragma unroll
    for (int kk = 0; kk < 2; ++kk) {
      bf16x8 af[4], bfv[4];
#pragma unroll
      for (int f = 0; f < 4; ++f) {
        af[f]  = *(const bf16x8*)(Ar + (wr * 64 + f * 16 + r) * 128 + kk * 64 + g * 16);
        bfv[f] = *(const bf16x8*)(Br + (wc * 64 + f * 16 + r) * 128 + kk * 64 + g * 16);
      }
#pragma unroll
      for (int fm = 0; fm < 4; ++fm)
#pragma unroll
        for (int fn = 0; fn < 4; ++fn)
          acc[fm][fn] = __builtin_amdgcn_mfma_f32_16x16x32_bf16(af[fm], bfv[fn], acc[fm][fn], 0, 0, 0);
    }
    __syncthreads();
  }

  if (MODE == 0) {
    const int which = n0 >> 10;  // 0=q 1=k 2=v (128 | 1024, so uniform per block)
    const float* bias = (which == 0) ? bias0 : (which == 1) ? bias1 : bias2;
#pragma unroll
    for (int fm = 0; fm < 4; ++fm) {
#pragma unroll
      for (int fn = 0; fn < 4; ++fn) {
        const int n = n0 + wc * 64 + fn * 16 + r;
        const int nn = n & 1023;
        const int h = nn >> 6, d = nn & 63;
        const float bvl = bias[nn];
#pragma unroll
        for (int j = 0; j < 4; ++j) {
          const int mm = m0 + wr * 64 + fm * 16 + 4 * g + j;
          const int b = mm >> 11, tt = mm & 2047;
          const unsigned short bits = f2bf(acc[fm][fn][j] + bvl);
          if (which == 2)
            vto[((size_t)((b * NHEAD + h) * 64 + d)) * TSEQ + tt] = bits;  // V^T [bh][d][t]
          else if (which == 1)
            ko[(((size_t)(b * NHEAD + h)) * TSEQ + tt) * 64 + d] = bits;
          else
            qo[(((size_t)(b * NHEAD + h)) * TSEQ + tt) * 64 + d] = bits;
        }
      }
    }
  } else {
#pragma unroll
    for (int fm = 0; fm < 4; ++fm)
#pragma unroll
      for (int fn = 0; fn < 4; ++fn) {
        const int n = n0 + wc * 64 + fn * 16 + r;
        const float bvl = bias0[n];
#pragma unroll
        for (int j = 0; j < 4; ++j) {
          const int mm = m0 + wr * 64 + fm * 16 + 4 * g + j;
          outf[(size_t)mm * N + n] = acc[fm][fn][j] + bvl;
        }
      }
  }
}

// ---------------- flash attention (causal) ----------------
// grid = B*H*(T/64); block 256 = 4 independent waves; wave owns 16 q-rows.
// K, V^T fragments read from global (L2-resident). P re-layout via padded LDS.

__global__ void attn_fwd(const unsigned short* __restrict__ Qm,
                         const unsigned short* __restrict__ Km,
                         const unsigned short* __restrict__ Vtm,
                         unsigned short* __restrict__ Om) {
  const int tid = threadIdx.x;
  const int lane = tid & 63;
  const int wv = tid >> 6;
  const int g = lane >> 4, r = lane & 15;
  const int blk = blockIdx.x;
  const int bh = blk >> 5;
  const int q0 = ((blk & 31) << 6) + wv * 16;

  const unsigned short* Qp = Qm + (size_t)bh * TSEQ * 64;
  const unsigned short* Kp = Km + (size_t)bh * TSEQ * 64;
  const unsigned short* Vp = Vtm + (size_t)bh * 64 * TSEQ;

  bf16x8 qf[2];
  qf[0] = *(const bf16x8*)(Qp + (size_t)(q0 + r) * 64 + g * 8);
  qf[1] = *(const bf16x8*)(Qp + (size_t)(q0 + r) * 64 + 32 + g * 8);

  __shared__ unsigned short Pl[4][16][72];  // per-wave P tile, +8 pad (2-way banks)

  f32x4 oacc[4] = {};
  float mrow[4], lrow[4];
#pragma unroll
  for (int j = 0; j < 4; ++j) { mrow[j] = -__builtin_inff(); lrow[j] = 0.f; }

  const int kv_end = q0 + 16;
  for (int kv0 = 0; kv0 < kv_end; kv0 += 64) {
    // S = Q K^T for 64 kv cols (4 fragments of 16)
    f32x4 s[4];
#pragma unroll
    for (int t = 0; t < 4; ++t) {
      const unsigned short* kb = Kp + (size_t)(kv0 + t * 16 + r) * 64 + g * 8;
      f32x4 a = {0.f, 0.f, 0.f, 0.f};
      a = __builtin_amdgcn_mfma_f32_16x16x32_bf16(qf[0], *(const bf16x8*)kb, a, 0, 0, 0);
      a = __builtin_amdgcn_mfma_f32_16x16x32_bf16(qf[1], *(const bf16x8*)(kb + 32), a, 0, 0, 0);
      s[t] = a;
    }
    // online softmax per q-row (row = 4g+j across lanes sharing g)
    float rs[4];
#pragma unroll
    for (int j = 0; j < 4; ++j) {
      const int qi = q0 + 4 * g + j;
      float mx = -__builtin_inff();
#pragma unroll
      for (int t = 0; t < 4; ++t) {
        const int kv = kv0 + t * 16 + r;
        float sv = s[t][j] * 0.125f;
        sv = (kv <= qi) ? sv : -__builtin_inff();
        s[t][j] = sv;
        mx = fmaxf(mx, sv);
      }
      mx = fmaxf(mx, __shfl_xor(mx, 1));
      mx = fmaxf(mx, __shfl_xor(mx, 2));
      mx = fmaxf(mx, __shfl_xor(mx, 4));
      mx = fmaxf(mx, __shfl_xor(mx, 8));
      const float mnew = fmaxf(mrow[j], mx);
      rs[j] = __expf(mrow[j] - mnew);
      float ts = 0.f;
#pragma unroll
      for (int t = 0; t < 4; ++t) {
        const float p = __expf(s[t][j] - mnew);
        s[t][j] = p;
        ts += p;
      }
      ts += __shfl_xor(ts, 1);
      ts += __shfl_xor(ts, 2);
      ts += __shfl_xor(ts, 4);
      ts += __shfl_xor(ts, 8);
      lrow[j] = lrow[j] * rs[j] + ts;
      mrow[j] = mnew;
    }
#pragma unroll
    for (int df = 0; df < 4; ++df)
#pragma unroll
      for (int j = 0; j < 4; ++j) oacc[df][j] *= rs[j];
    // P (C-frag layout) -> LDS -> A-frag layout
#pragma unroll
    for (int t = 0; t < 4; ++t)
#pragma unroll
      for (int j = 0; j < 4; ++j)
        Pl[wv][4 * g + j][t * 16 + r] = f2bf(s[t][j]);
    asm volatile("s_waitcnt lgkmcnt(0)" ::: "memory");
    // O += P * V   (V^T rows are contiguous along t)
#pragma unroll
    for (int kk = 0; kk < 2; ++kk) {
      bf16x8 pa = *(const bf16x8*)(&Pl[wv][r][kk * 32 + g * 8]);
#pragma unroll
      for (int df = 0; df < 4; ++df) {
        const unsigned short* vb = Vp + (size_t)(df * 16 + r) * TSEQ + kv0 + kk * 32 + g * 8;
        oacc[df] = __builtin_amdgcn_mfma_f32_16x16x32_bf16(pa, *(const bf16x8*)vb, oacc[df], 0, 0, 0);
      }
    }
  }
  // write concat layout [B,T,H*64] bf16
  const int b = bh >> 4, h = bh & 15;
#pragma unroll
  for (int df = 0; df < 4; ++df)
#pragma unroll
    for (int j = 0; j < 4; ++j) {
      const int trow = q0 + 4 * g + j;
      const float ov = oacc[df][j] / lrow[j];
      Om[((size_t)(b * TSEQ + trow)) * 1024 + h * 64 + df * 16 + r] = f2bf(ov);
    }
}

// ---------------- launch ----------------

extern "C" void kernel_launch(void* const* d_in, const int* in_sizes, int n_in,
                              void* d_out, int out_size, void* d_ws, size_t ws_size,
                              hipStream_t stream) {
  const float* x  = (const float*)d_in[0];
  const float* Wq = (const float*)d_in[1];
  const float* bq = (const float*)d_in[2];
  const float* Wk = (const float*)d_in[3];
  const float* bk = (const float*)d_in[4];
  const float* Wv = (const float*)d_in[5];
  const float* bv = (const float*)d_in[6];
  const float* Wo = (const float*)d_in[7];
  const float* bo = (const float*)d_in[8];
  float* out = (float*)d_out;

  // workspace carve (bf16 buffers as ushort). xb is reused as attention output.
  unsigned short* xb  = (unsigned short*)d_ws;               // 8192*1024
  unsigned short* btq = xb + (size_t)8192 * 1024;            // 3072*1024
  unsigned short* wot = btq + (size_t)3072 * 1024;           // 1024*1024
  unsigned short* qb  = wot + (size_t)1024 * 1024;           // 64*2048*64
  unsigned short* kb  = qb + (size_t)64 * 2048 * 64;
  unsigned short* vtb = kb + (size_t)64 * 2048 * 64;

  cast_x_kernel<<<8192, 256, 0, stream>>>((const float4*)x, (ushort4*)xb);
  repack_wqkv<<<dim3(16, 16, 3), 256, 0, stream>>>(Wq, Wk, Wv, btq);
  repack_wo<<<dim3(16, 16), 256, 0, stream>>>(Wo, wot);

  // QKV: [8192,1024] x [1024,3072]
  gemm_bt<0><<<dim3(64, 24), 256, 0, stream>>>(xb, btq, bq, bk, bv, qb, kb, vtb,
                                               nullptr, 8192, 3072, 1024);
  // attention: 64 bh * 32 q-blocks
  attn_fwd<<<2048, 256, 0, stream>>>(qb, kb, vtb, xb);
  // O-proj: [8192,1024] x [1024,1024] -> f32 out
  gemm_bt<1><<<dim3(64, 8), 256, 0, stream>>>(xb, wot, bo, nullptr, nullptr,
                                              nullptr, nullptr, nullptr, out,
                                              8192, 1024, 1024);
}

// Round 2
// 244.059 us; speedup vs baseline: 2.4472x; 2.4472x over previous
//
#include <hip/hip_runtime.h>
#include <stdint.h>

#define TSEQ 2048
#define NHEAD 16

typedef __attribute__((ext_vector_type(8))) short bf16x8;
typedef __attribute__((ext_vector_type(4))) float f32x4;

__device__ __forceinline__ unsigned short f2bf(float f) {
  union { float f; uint32_t u; } c;
  c.f = f;
  uint32_t u = c.u;
  u += 0x7fffu + ((u >> 16) & 1u);   // round-nearest-even
  return (unsigned short)(u >> 16);
}

__device__ __forceinline__ uint32_t pk2(float a, float b) {
  return (uint32_t)f2bf(a) | ((uint32_t)f2bf(b) << 16);
}

using as3_void  = __attribute__((address_space(3))) void;
using as1_cvoid = const __attribute__((address_space(1))) void;

__device__ __forceinline__ void gld_lds16(const void* g, void* l) {
  // async global->LDS, 16B per lane; LDS dest = wave-uniform base + lane*16
  __builtin_amdgcn_global_load_lds((as1_cvoid*)g, (as3_void*)l, 16, 0, 0);
}

// ---------------- prep kernels ----------------

__global__ void cast_x_kernel(const float4* __restrict__ x, ushort4* __restrict__ xb) {
  int i = blockIdx.x * 256 + threadIdx.x;
  float4 v = x[i];
  ushort4 o;
  o.x = f2bf(v.x); o.y = f2bf(v.y); o.z = f2bf(v.z); o.w = f2bf(v.w);
  xb[i] = o;
}

// Wq/Wk/Wv [H,C,HD] f32 -> BT [(which*1024 + h*64 + d)][c] bf16
__global__ void repack_wqkv(const float* __restrict__ Wq, const float* __restrict__ Wk,
                            const float* __restrict__ Wv, unsigned short* __restrict__ BT) {
  __shared__ unsigned short tile[64][72];
  const float* W = (blockIdx.z == 0) ? Wq : (blockIdx.z == 1) ? Wk : Wv;
  const int h = blockIdx.y;
  const int c0 = blockIdx.x * 64;
  const int t = threadIdx.x;
  const float* src = W + ((size_t)h * 1024 + c0) * 64;
#pragma unroll
  for (int p = 0; p < 16; ++p) {
    int idx = p * 256 + t;
    int cc = idx >> 6, d = idx & 63;
    tile[cc][d] = f2bf(src[(size_t)cc * 64 + d]);
  }
  __syncthreads();
  unsigned short* dst = BT + ((size_t)blockIdx.z * 1024 + (size_t)h * 64) * 1024 + c0;
#pragma unroll
  for (int p = 0; p < 16; ++p) {
    int idx = p * 256 + t;
    int d = idx >> 6, cc = idx & 63;
    dst[(size_t)d * 1024 + cc] = tile[cc][d];
  }
}

// Wo [C,C] f32 -> WoT [n][k] bf16 (transpose)
__global__ void repack_wo(const float* __restrict__ Wo, unsigned short* __restrict__ WoT) {
  __shared__ unsigned short tile[64][72];
  const int k0 = blockIdx.x * 64;
  const int n0 = blockIdx.y * 64;
  const int t = threadIdx.x;
#pragma unroll
  for (int p = 0; p < 16; ++p) {
    int idx = p * 256 + t;
    int kk = idx >> 6, nn = idx & 63;
    tile[kk][nn] = f2bf(Wo[(size_t)(k0 + kk) * 1024 + n0 + nn]);
  }
  __syncthreads();
#pragma unroll
  for (int p = 0; p < 16; ++p) {
    int idx = p * 256 + t;
    int nn = idx >> 6, kk = idx & 63;
    WoT[(size_t)(n0 + nn) * 1024 + k0 + kk] = tile[kk][nn];
  }
}

// ---------------- GEMM: C = A[M,K] * BT[N,K]^T + bias ----------------
// 128x128 tile, BK=64, 256 thr = 4 waves (2x2), 4x4 16x16x32 frags/wave.
// MODE 0: QKV epilogue. q -> [bh][t][64] linear bf16.
//         k -> [bh] chunked [t][d ^ ((t&7)<<3)]           (bank-swizzled)
//         vT -> [bh][t>>6 chunk][d][ (t&63) ^ ((d&7)<<3) ] (bank-swizzled)
// MODE 1: f32 output + bias

template <int MODE>
__global__ __launch_bounds__(256) void gemm_bt(
    const unsigned short* __restrict__ A, const unsigned short* __restrict__ BTm,
    const float* __restrict__ bias0, const float* __restrict__ bias1,
    const float* __restrict__ bias2,
    unsigned short* __restrict__ qo, unsigned short* __restrict__ ko,
    unsigned short* __restrict__ vto, float* __restrict__ outf,
    int M, int N, int K) {
  __shared__ __align__(16) unsigned short As[128 * 64];
  __shared__ __align__(16) unsigned short Bs[128 * 64];
  const int tid = threadIdx.x;
  const int lane = tid & 63;
  const int wv = tid >> 6;
  const int wr = wv >> 1, wc = wv & 1;
  const int g = lane >> 4, r = lane & 15;
  const int m0 = blockIdx.x * 128;
  const int n0 = blockIdx.y * 128;

  f32x4 acc[4][4] = {};

  const int arow = tid >> 3;            // 0..31
  const int acol = (tid & 7) * 8;       // 0..56
  const unsigned short* Ab = A + (size_t)(m0 + arow) * K + acol;
  const unsigned short* Bb = BTm + (size_t)(n0 + arow) * K + acol;
  char* AsB = (char*)As + wv * 1024;
  char* BsB = (char*)Bs + wv * 1024;

  for (int k0 = 0; k0 < K; k0 += 64) {
#pragma unroll
    for (int i = 0; i < 4; ++i) {
      gld_lds16(Ab + (size_t)i * 32 * K + k0, AsB + i * 4096);
      gld_lds16(Bb + (size_t)i * 32 * K + k0, BsB + i * 4096);
    }
    __syncthreads();
    const char* Ar = (const char*)As;
    const char* Br = (const char*)Bs;
#pragma unroll
    for (int kk = 0; kk < 2; ++kk) {
      bf16x8 af[4], bfv[4];
#pragma unroll
      for (int f = 0; f < 4; ++f) {
        af[f]  = *(const bf16x8*)(Ar + (wr * 64 + f * 16 + r) * 128 + kk * 64 + g * 16);
        bfv[f] = *(const bf16x8*)(Br + (wc * 64 + f * 16 + r) * 128 + kk * 64 + g * 16);
      }
#pragma unroll
      for (int fm = 0; fm < 4; ++fm)
#pragma unroll
        for (int fn = 0; fn < 4; ++fn)
          acc[fm][fn] = __builtin_amdgcn_mfma_f32_16x16x32_bf16(af[fm], bfv[fn], acc[fm][fn], 0, 0, 0);
    }
    __syncthreads();
  }

  if (MODE == 0) {
    const int which = n0 >> 10;  // 0=q 1=k 2=v (uniform per block)
    const float* bias = (which == 0) ? bias0 : (which == 1) ? bias1 : bias2;
#pragma unroll
    for (int fm = 0; fm < 4; ++fm) {
#pragma unroll
      for (int fn = 0; fn < 4; ++fn) {
        const int n = n0 + wc * 64 + fn * 16 + r;
        const int nn = n & 1023;
        const int h = nn >> 6, d = nn & 63;
        const float bvl = bias[nn];
#pragma unroll
        for (int j = 0; j < 4; ++j) {
          const int mm = m0 + wr * 64 + fm * 16 + 4 * g + j;
          const int b = mm >> 11, tt = mm & 2047;
          const size_t bhb = (size_t)(b * NHEAD + h) * 131072;
          const unsigned short bits = f2bf(acc[fm][fn][j] + bvl);
          if (which == 2)
            vto[bhb + (size_t)(tt >> 6) * 4096 + (size_t)d * 64 + ((tt & 63) ^ ((d & 7) << 3))] = bits;
          else if (which == 1)
            ko[bhb + (size_t)tt * 64 + (d ^ ((tt & 7) << 3))] = bits;
          else
            qo[bhb + (size_t)tt * 64 + d] = bits;
        }
      }
    }
  } else {
#pragma unroll
    for (int fm = 0; fm < 4; ++fm)
#pragma unroll
      for (int fn = 0; fn < 4; ++fn) {
        const int n = n0 + wc * 64 + fn * 16 + r;
        const float bvl = bias0[n];
#pragma unroll
        for (int j = 0; j < 4; ++j) {
          const int mm = m0 + wr * 64 + fm * 16 + 4 * g + j;
          outf[(size_t)mm * N + n] = acc[fm][fn][j] + bvl;
        }
      }
  }
}

// ---------------- flash attention (causal), LDS-staged, swapped QK^T ----------------
// grid = 16 qp * 64 bh (heavy qp first); block 256 = 4 waves.
// Block owns 128 q rows; wave wv owns rows {qp*128+wv*16..+15} and {+64}.
// K,V tiles (64 kv x 64 d, bank-swizzled) double-buffered in LDS via global_load_lds.
// Swapped QK^T: S^T = mfma(K, Q) -> lane owns q=r; softmax = in-lane + 2 shuffles.

__global__ __launch_bounds__(256) void attn_fwd(const unsigned short* __restrict__ Qm,
                                                const unsigned short* __restrict__ Km,
                                                const unsigned short* __restrict__ Vtm,
                                                unsigned short* __restrict__ Om) {
  __shared__ __align__(16) unsigned short Ks[2][4096];
  __shared__ __align__(16) unsigned short Vs[2][4096];
  __shared__ __align__(16) unsigned short Pl[4][16][72];

  const int tid = threadIdx.x, lane = tid & 63, wv = tid >> 6;
  const int g = lane >> 4, r = lane & 15;
  const int bh = blockIdx.x & 63;
  const int qp = 15 - (blockIdx.x >> 6);      // heavy blocks dispatch first

  const unsigned short* Qp = Qm + (size_t)bh * 131072;
  const unsigned short* Kp = Km + (size_t)bh * 131072;
  const unsigned short* Vp = Vtm + (size_t)bh * 131072;

  const int qb[2] = {qp * 128 + wv * 16, qp * 128 + 64 + wv * 16};

  bf16x8 qf[2][2];
#pragma unroll
  for (int mi = 0; mi < 2; ++mi)
#pragma unroll
    for (int h2 = 0; h2 < 2; ++h2)
      qf[mi][h2] = *(const bf16x8*)(Qp + (size_t)(qb[mi] + r) * 64 + h2 * 32 + g * 8);

  f32x4 oacc[2][4] = {};
  float m_[2] = {-__builtin_inff(), -__builtin_inff()};
  float l_[2] = {0.f, 0.f};
  const int qi = r;  // per-lane q row offset within frag

#define STAGE(buf, c) do {                                                       \
    const unsigned short* kg_ = Kp + (size_t)(c) * 4096;                         \
    const unsigned short* vg_ = Vp + (size_t)(c) * 4096;                         \
    const int o0_ = wv * 1024;                                                   \
    gld_lds16(kg_ + (o0_ >> 1) + lane * 8, (char*)Ks[buf] + o0_);                \
    gld_lds16(vg_ + (o0_ >> 1) + lane * 8, (char*)Vs[buf] + o0_);                \
    gld_lds16(kg_ + ((o0_ + 4096) >> 1) + lane * 8, (char*)Ks[buf] + o0_ + 4096);\
    gld_lds16(vg_ + ((o0_ + 4096) >> 1) + lane * 8, (char*)Vs[buf] + o0_ + 4096);\
  } while (0)

  const int nt = qp * 2 + 2;
  STAGE(0, 0);
  __syncthreads();

  for (int t = 0; t < nt; ++t) {
    const int cur = t & 1;
    if (t + 1 < nt) STAGE(cur ^ 1, t + 1);

    // load K and V fragments (shared by both m-frags); swizzled reads
    const char* KsT = (const char*)Ks[cur];
    const char* VsT = (const char*)Vs[cur];
    const int sw = (r & 7) << 4;
    bf16x8 kf[4][2], vf[4][2];
#pragma unroll
    for (int tt = 0; tt < 4; ++tt) {
      const int rowb = (tt * 16 + r) * 128;
#pragma unroll
      for (int kk = 0; kk < 2; ++kk) {
        const int cb = (kk * 64 + g * 16) ^ sw;
        kf[tt][kk] = *(const bf16x8*)(KsT + rowb + cb);
        vf[tt][kk] = *(const bf16x8*)(VsT + rowb + cb);
      }
    }

#pragma unroll
    for (int mi = 0; mi < 2; ++mi) {
      const int qbm = qb[mi];
      if (t * 64 > qbm + 15) continue;   // frag fully masked (wave-uniform)

      // S^T[kv][q] = K Q^T : lane holds q = r, kv = tt*16 + 4g + j
      f32x4 sT[4];
#pragma unroll
      for (int tt = 0; tt < 4; ++tt) {
        f32x4 a = {0.f, 0.f, 0.f, 0.f};
        a = __builtin_amdgcn_mfma_f32_16x16x32_bf16(kf[tt][0], qf[mi][0], a, 0, 0, 0);
        a = __builtin_amdgcn_mfma_f32_16x16x32_bf16(kf[tt][1], qf[mi][1], a, 0, 0, 0);
        sT[tt] = a;
      }
      // mask + scale + row max (row = q = r, uniform across g after 2 shuffles)
      const int qg = qbm + qi;           // this lane's global q row
      float mx = -__builtin_inff();
#pragma unroll
      for (int tt = 0; tt < 4; ++tt)
#pragma unroll
        for (int j = 0; j < 4; ++j) {
          const int kv = t * 64 + tt * 16 + 4 * g + j;
          float sv = sT[tt][j] * 0.125f;
          sv = (kv <= qg) ? sv : -__builtin_inff();
          sT[tt][j] = sv;
          mx = fmaxf(mx, sv);
        }
      mx = fmaxf(mx, __shfl_xor(mx, 16));
      mx = fmaxf(mx, __shfl_xor(mx, 32));
      const float mnew = fmaxf(m_[mi], mx);
      const float rs = __expf(m_[mi] - mnew);
      m_[mi] = mnew;
      float ts = 0.f;
#pragma unroll
      for (int tt = 0; tt < 4; ++tt)
#pragma unroll
        for (int j = 0; j < 4; ++j) {
          const float p = __expf(sT[tt][j] - mnew);
          sT[tt][j] = p;
          ts += p;
        }
      ts += __shfl_xor(ts, 16);
      ts += __shfl_xor(ts, 32);
      l_[mi] = l_[mi] * rs + ts;

      // P[q=r][kv]: lane's j-values contiguous -> one b64 write per tt
#pragma unroll
      for (int tt = 0; tt < 4; ++tt) {
        uint2 w;
        w.x = pk2(sT[tt][0], sT[tt][1]);
        w.y = pk2(sT[tt][2], sT[tt][3]);
        *(uint2*)&Pl[wv][r][tt * 16 + 4 * g] = w;
      }
      asm volatile("s_waitcnt lgkmcnt(0)" ::: "memory");

      // broadcast rescale factors to C-frag rows (q = 4g+j held at lane 4g+j)
      float rsb[4];
#pragma unroll
      for (int j = 0; j < 4; ++j) rsb[j] = __shfl(rs, 4 * g + j);
#pragma unroll
      for (int df = 0; df < 4; ++df)
#pragma unroll
        for (int j = 0; j < 4; ++j) oacc[mi][df][j] *= rsb[j];

      // O += P V : A = P[q rows][kv], B = V^T[d rows][kv]
#pragma unroll
      for (int kk = 0; kk < 2; ++kk) {
        const bf16x8 pa = *(const bf16x8*)&Pl[wv][r][kk * 32 + g * 8];
#pragma unroll
        for (int df = 0; df < 4; ++df)
          oacc[mi][df] = __builtin_amdgcn_mfma_f32_16x16x32_bf16(pa, vf[df][kk], oacc[mi][df], 0, 0, 0);
      }
    }
    __syncthreads();
  }
#undef STAGE

  // write concat layout [B,T,H*64] bf16
  const int b = bh >> 4, h = bh & 15;
#pragma unroll
  for (int mi = 0; mi < 2; ++mi) {
    float lb[4];
#pragma unroll
    for (int j = 0; j < 4; ++j) lb[j] = __shfl(l_[mi], 4 * g + j);
#pragma unroll
    for (int df = 0; df < 4; ++df)
#pragma unroll
      for (int j = 0; j < 4; ++j) {
        const int trow = qb[mi] + 4 * g + j;
        const float ov = oacc[mi][df][j] / lb[j];
        Om[((size_t)(b * TSEQ + trow)) * 1024 + h * 64 + df * 16 + r] = f2bf(ov);
      }
  }
}

// ---------------- launch ----------------

extern "C" void kernel_launch(void* const* d_in, const int* in_sizes, int n_in,
                              void* d_out, int out_size, void* d_ws, size_t ws_size,
                              hipStream_t stream) {
  const float* x  = (const float*)d_in[0];
  const float* Wq = (const float*)d_in[1];
  const float* bq = (const float*)d_in[2];
  const float* Wk = (const float*)d_in[3];
  const float* bk = (const float*)d_in[4];
  const float* Wv = (const float*)d_in[5];
  const float* bv = (const float*)d_in[6];
  const float* Wo = (const float*)d_in[7];
  const float* bo = (const float*)d_in[8];
  float* out = (float*)d_out;

  unsigned short* xb  = (unsigned short*)d_ws;               // 8192*1024
  unsigned short* btq = xb + (size_t)8192 * 1024;            // 3072*1024
  unsigned short* wot = btq + (size_t)3072 * 1024;           // 1024*1024
  unsigned short* qb  = wot + (size_t)1024 * 1024;           // 64*2048*64
  unsigned short* kb  = qb + (size_t)64 * 2048 * 64;
  unsigned short* vtb = kb + (size_t)64 * 2048 * 64;

  cast_x_kernel<<<8192, 256, 0, stream>>>((const float4*)x, (ushort4*)xb);
  repack_wqkv<<<dim3(16, 16, 3), 256, 0, stream>>>(Wq, Wk, Wv, btq);
  repack_wo<<<dim3(16, 16), 256, 0, stream>>>(Wo, wot);

  // QKV: [8192,1024] x [1024,3072]
  gemm_bt<0><<<dim3(64, 24), 256, 0, stream>>>(xb, btq, bq, bk, bv, qb, kb, vtb,
                                               nullptr, 8192, 3072, 1024);
  // attention: 16 qp (heavy first) x 64 bh
  attn_fwd<<<1024, 256, 0, stream>>>(qb, kb, vtb, xb);
  // O-proj: [8192,1024] x [1024,1024] -> f32 out
  gemm_bt<1><<<dim3(64, 8), 256, 0, stream>>>(xb, wot, bo, nullptr, nullptr,
                                              nullptr, nullptr, nullptr, out,
                                              8192, 1024, 1024);
}

// Round 3
// 235.869 us; speedup vs baseline: 2.5321x; 1.0347x over previous
//
#include <hip/hip_runtime.h>
#include <stdint.h>

#define TSEQ 2048
#define NHEAD 16

typedef __attribute__((ext_vector_type(8))) short bf16x8;
typedef __attribute__((ext_vector_type(4))) float f32x4;

__device__ __forceinline__ unsigned short f2bf(float f) {
  union { float f; uint32_t u; } c;
  c.f = f;
  uint32_t u = c.u;
  u += 0x7fffu + ((u >> 16) & 1u);   // round-nearest-even
  return (unsigned short)(u >> 16);
}

__device__ __forceinline__ uint32_t pk2(float a, float b) {
  return (uint32_t)f2bf(a) | ((uint32_t)f2bf(b) << 16);
}

using as3_void  = __attribute__((address_space(3))) void;
using as1_cvoid = const __attribute__((address_space(1))) void;

__device__ __forceinline__ void gld_lds16(const void* g, void* l) {
  // async global->LDS, 16B/lane; LDS dest = wave-uniform base + lane*16
  __builtin_amdgcn_global_load_lds((as1_cvoid*)g, (as3_void*)l, 16, 0, 0);
}

#define VMCNT4() asm volatile("s_waitcnt vmcnt(4)" ::: "memory")
#define VMCNT0() asm volatile("s_waitcnt vmcnt(0)" ::: "memory")
#define LGKM0()  do { asm volatile("s_waitcnt lgkmcnt(0)" ::: "memory"); __builtin_amdgcn_sched_barrier(0); } while (0)

// ---------------- prep kernels (produce K-swizzled global layouts) ----------------
// GEMM operand layout: X'[row][k] = X[row][k ^ ((row&7)<<3)] within each 64-elem k-block.
// gld_lds then fills LDS linearly; ds_read applies the same XOR -> bank-balanced.

__global__ void cast_x_kernel(const float4* __restrict__ x, unsigned short* __restrict__ xb) {
  int i = blockIdx.x * 256 + threadIdx.x;   // group of 4 elems
  float4 v = x[i];
  int e = i * 4;
  int m = e >> 10, k = e & 1023;
  int ks = k ^ ((m & 7) << 3);
  ushort4 o;
  o.x = f2bf(v.x); o.y = f2bf(v.y); o.z = f2bf(v.z); o.w = f2bf(v.w);
  *(ushort4*)(xb + (size_t)m * 1024 + ks) = o;
}

// Wq/Wk/Wv [H,C,HD] f32 -> BT[(which*1024 + h*64 + d)][c ^ swz(d)] bf16
__global__ void repack_wqkv(const float* __restrict__ Wq, const float* __restrict__ Wk,
                            const float* __restrict__ Wv, unsigned short* __restrict__ BT) {
  __shared__ unsigned short tile[64][72];
  const float* W = (blockIdx.z == 0) ? Wq : (blockIdx.z == 1) ? Wk : Wv;
  const int h = blockIdx.y;
  const int c0 = blockIdx.x * 64;
  const int t = threadIdx.x;
  const float* src = W + ((size_t)h * 1024 + c0) * 64;
#pragma unroll
  for (int p = 0; p < 16; ++p) {
    int idx = p * 256 + t;
    int cc = idx >> 6, d = idx & 63;
    tile[cc][d] = f2bf(src[(size_t)cc * 64 + d]);
  }
  __syncthreads();
  unsigned short* dst = BT + ((size_t)blockIdx.z * 1024 + (size_t)h * 64) * 1024 + c0;
#pragma unroll
  for (int p = 0; p < 16; ++p) {
    int idx = p * 256 + t;
    int d = idx >> 6, cc = idx & 63;
    dst[(size_t)d * 1024 + (cc ^ ((d & 7) << 3))] = tile[cc][d];
  }
}

// Wo [C,C] f32 -> WoT[n][k ^ swz(n)] bf16 (transpose + swizzle)
__global__ void repack_wo(const float* __restrict__ Wo, unsigned short* __restrict__ WoT) {
  __shared__ unsigned short tile[64][72];
  const int k0 = blockIdx.x * 64;
  const int n0 = blockIdx.y * 64;
  const int t = threadIdx.x;
#pragma unroll
  for (int p = 0; p < 16; ++p) {
    int idx = p * 256 + t;
    int kk = idx >> 6, nn = idx & 63;
    tile[kk][nn] = f2bf(Wo[(size_t)(k0 + kk) * 1024 + n0 + nn]);
  }
  __syncthreads();
#pragma unroll
  for (int p = 0; p < 16; ++p) {
    int idx = p * 256 + t;
    int nn = idx >> 6, kk = idx & 63;
    WoT[(size_t)(n0 + nn) * 1024 + k0 + (kk ^ ((nn & 7) << 3))] = tile[kk][nn];
  }
}

// ---------------- 256x256 8-phase GEMM (T2+T3+T4+T5) ----------------
// C = A[M,K] * BT[N,K]^T + bias; A,BT in K-swizzled layout.
// 512 thr = 8 waves (2M x 4N, interleaved frags): wave (wr,wc) M-frag i at
// row wr*16+i*32, N-frag j at col wc*16+j*64. 4 phases per K-tile:
//   P1: reads A-half0 + B-half0, stages A0'; P2: reads B-half1, stages B0';
//   P3: reads A-half1, stages B1';           P4: no reads, stages A1'.
// vmcnt(4) at P1/P2/P3 retires exactly the needed half-tile; never drains to 0
// in steady state (last K-tile peels with vmcnt(0)).

template <int MODE>
__global__ __launch_bounds__(512, 2) void gemm8(
    const unsigned short* __restrict__ A, const unsigned short* __restrict__ BTm,
    const float* __restrict__ bias0, const float* __restrict__ bias1,
    const float* __restrict__ bias2,
    unsigned short* __restrict__ qo, unsigned short* __restrict__ ko,
    unsigned short* __restrict__ vto, float* __restrict__ outf,
    int K, int N) {
  __shared__ __align__(16) char lds[131072];  // 2 buf x (A 32K + B 32K)
  const int tid = threadIdx.x, lane = tid & 63, w = tid >> 6;
  const int wr = w >> 2, wc = w & 3;
  const int g = lane >> 4, r = lane & 15;
  const int m0 = blockIdx.x * 256, n0 = blockIdx.y * 256;
  const int xr = (r & 7) << 4;

  const int srow = w * 8 + (lane >> 3);
  const int scol = (lane & 7) * 8;
  const unsigned short* Ag = A + (size_t)(m0 + srow) * K + scol;
  const unsigned short* Bg = BTm + (size_t)(n0 + srow) * K + scol;
  char* const ldsw = lds + w * 1024;

  f32x4 acc[8][4] = {};
  bf16x8 a_[4][2], b_[2][2][2];

#define STAGE2(isB, h, buf, kt) do {                                        \
    const unsigned short* gp_ = (isB) ? Bg : Ag;                            \
    char* lp_ = ldsw + (buf) * 65536 + (isB) * 32768 + (h) * 16384;         \
    gld_lds16(gp_ + (size_t)((h) * 128) * K + (kt) * 64, lp_);              \
    gld_lds16(gp_ + (size_t)((h) * 128 + 64) * K + (kt) * 64, lp_ + 8192);  \
  } while (0)

#define RDA(qa, cb) do {                                                    \
    _Pragma("unroll") for (int ii = 0; ii < 4; ++ii) {                      \
      const char* p_ = (cb) + (wr * 16 + r + (qa) * 128 + ii * 32) * 128;   \
      a_[ii][0] = *(const bf16x8*)(p_ + ((g * 16) ^ xr));                   \
      a_[ii][1] = *(const bf16x8*)(p_ + ((64 + g * 16) ^ xr));              \
    } } while (0)

#define RDB(qb, cb) do {                                                    \
    _Pragma("unroll") for (int jj = 0; jj < 2; ++jj) {                      \
      const char* p_ = (cb) + 32768 + (wc * 16 + r + ((qb) * 2 + jj) * 64) * 128; \
      b_[qb][jj][0] = *(const bf16x8*)(p_ + ((g * 16) ^ xr));               \
      b_[qb][jj][1] = *(const bf16x8*)(p_ + ((64 + g * 16) ^ xr));          \
    } } while (0)

#define MFMAPH(qa, qb) do {                                                 \
    __builtin_amdgcn_s_setprio(1);                                          \
    _Pragma("unroll") for (int ii = 0; ii < 4; ++ii)                        \
    _Pragma("unroll") for (int jj = 0; jj < 2; ++jj) {                      \
      acc[(qa)*4+ii][(qb)*2+jj] = __builtin_amdgcn_mfma_f32_16x16x32_bf16(  \
          a_[ii][0], b_[qb][jj][0], acc[(qa)*4+ii][(qb)*2+jj], 0, 0, 0);    \
      acc[(qa)*4+ii][(qb)*2+jj] = __builtin_amdgcn_mfma_f32_16x16x32_bf16(  \
          a_[ii][1], b_[qb][jj][1], acc[(qa)*4+ii][(qb)*2+jj], 0, 0, 0);    \
    }                                                                       \
    __builtin_amdgcn_s_setprio(0);                                          \
  } while (0)

  const int NT = K >> 6;
  // prologue: stage tile0 into buf0, order A0,B0,B1,A1 (matches phase needs)
  STAGE2(0, 0, 0, 0);
  STAGE2(1, 0, 0, 0);
  STAGE2(1, 1, 0, 0);
  STAGE2(0, 1, 0, 0);

  for (int t = 0; t < NT; ++t) {
    const int cur = t & 1, nxt = cur ^ 1;
    const char* cb = lds + cur * 65536;
    const bool st = (t + 1 < NT);
    // ---- P1 ----
    if (t == NT - 1) VMCNT0(); else VMCNT4();
    __builtin_amdgcn_s_barrier();
    __builtin_amdgcn_sched_barrier(0);
    RDA(0, cb); RDB(0, cb);
    if (st) STAGE2(0, 0, nxt, t + 1);
    LGKM0();
    MFMAPH(0, 0);
    // ---- P2 ----
    VMCNT4();
    __builtin_amdgcn_s_barrier();
    __builtin_amdgcn_sched_barrier(0);
    RDB(1, cb);
    if (st) STAGE2(1, 0, nxt, t + 1);
    LGKM0();
    MFMAPH(0, 1);
    // ---- P3 ----
    VMCNT4();
    __builtin_amdgcn_s_barrier();
    __builtin_amdgcn_sched_barrier(0);
    RDA(1, cb);
    if (st) STAGE2(1, 1, nxt, t + 1);
    LGKM0();
    MFMAPH(1, 0);
    // ---- P4 ----
    __builtin_amdgcn_s_barrier();
    __builtin_amdgcn_sched_barrier(0);
    if (st) STAGE2(0, 1, nxt, t + 1);
    MFMAPH(1, 1);
  }
#undef STAGE2
#undef RDA
#undef RDB
#undef MFMAPH

  if (MODE == 0) {
    const int which = n0 >> 10;  // 0=q 1=k 2=v (256 | 1024 -> uniform per block)
    const float* bias = (which == 0) ? bias0 : (which == 1) ? bias1 : bias2;
#pragma unroll
    for (int i = 0; i < 8; ++i) {
#pragma unroll
      for (int j = 0; j < 4; ++j) {
        const int n = n0 + wc * 16 + j * 64 + r;
        const int nn = n & 1023;
        const int h = nn >> 6, d = nn & 63;
        const float bvl = bias[nn];
#pragma unroll
        for (int jj = 0; jj < 4; ++jj) {
          const int mm = m0 + wr * 16 + i * 32 + 4 * g + jj;
          const int b = mm >> 11, tt = mm & 2047;
          const size_t bhb = (size_t)(b * NHEAD + h) * 131072;
          const unsigned short bits = f2bf(acc[i][j][jj] + bvl);
          if (which == 2)
            vto[bhb + (size_t)(tt >> 6) * 4096 + (size_t)d * 64 + ((tt & 63) ^ ((d & 7) << 3))] = bits;
          else if (which == 1)
            ko[bhb + (size_t)tt * 64 + (d ^ ((tt & 7) << 3))] = bits;
          else
            qo[bhb + (size_t)tt * 64 + d] = bits;
        }
      }
    }
  } else {
#pragma unroll
    for (int i = 0; i < 8; ++i)
#pragma unroll
      for (int j = 0; j < 4; ++j) {
        const int n = n0 + wc * 16 + j * 64 + r;
        const float bvl = bias0[n];
#pragma unroll
        for (int jj = 0; jj < 4; ++jj) {
          const int mm = m0 + wr * 16 + i * 32 + 4 * g + jj;
          outf[(size_t)mm * N + n] = acc[i][j][jj] + bvl;
        }
      }
  }
}

// ---------------- flash attention (causal), LDS-staged, swapped QK^T ----------------
// (unchanged from round 2 except output write is K-swizzled for the O-proj GEMM)

__global__ __launch_bounds__(256) void attn_fwd(const unsigned short* __restrict__ Qm,
                                                const unsigned short* __restrict__ Km,
                                                const unsigned short* __restrict__ Vtm,
                                                unsigned short* __restrict__ Om) {
  __shared__ __align__(16) unsigned short Ks[2][4096];
  __shared__ __align__(16) unsigned short Vs[2][4096];
  __shared__ __align__(16) unsigned short Pl[4][16][72];

  const int tid = threadIdx.x, lane = tid & 63, wv = tid >> 6;
  const int g = lane >> 4, r = lane & 15;
  const int bh = blockIdx.x & 63;
  const int qp = 15 - (blockIdx.x >> 6);      // heavy blocks dispatch first

  const unsigned short* Qp = Qm + (size_t)bh * 131072;
  const unsigned short* Kp = Km + (size_t)bh * 131072;
  const unsigned short* Vp = Vtm + (size_t)bh * 131072;

  const int qb[2] = {qp * 128 + wv * 16, qp * 128 + 64 + wv * 16};

  bf16x8 qf[2][2];
#pragma unroll
  for (int mi = 0; mi < 2; ++mi)
#pragma unroll
    for (int h2 = 0; h2 < 2; ++h2)
      qf[mi][h2] = *(const bf16x8*)(Qp + (size_t)(qb[mi] + r) * 64 + h2 * 32 + g * 8);

  f32x4 oacc[2][4] = {};
  float m_[2] = {-__builtin_inff(), -__builtin_inff()};
  float l_[2] = {0.f, 0.f};
  const int qi = r;

#define ASTAGE(buf, c) do {                                                      \
    const unsigned short* kg_ = Kp + (size_t)(c) * 4096;                         \
    const unsigned short* vg_ = Vp + (size_t)(c) * 4096;                         \
    const int o0_ = wv * 1024;                                                   \
    gld_lds16(kg_ + (o0_ >> 1) + lane * 8, (char*)Ks[buf] + o0_);                \
    gld_lds16(vg_ + (o0_ >> 1) + lane * 8, (char*)Vs[buf] + o0_);                \
    gld_lds16(kg_ + ((o0_ + 4096) >> 1) + lane * 8, (char*)Ks[buf] + o0_ + 4096);\
    gld_lds16(vg_ + ((o0_ + 4096) >> 1) + lane * 8, (char*)Vs[buf] + o0_ + 4096);\
  } while (0)

  const int nt = qp * 2 + 2;
  ASTAGE(0, 0);
  __syncthreads();

  for (int t = 0; t < nt; ++t) {
    const int cur = t & 1;
    if (t + 1 < nt) ASTAGE(cur ^ 1, t + 1);

    const char* KsT = (const char*)Ks[cur];
    const char* VsT = (const char*)Vs[cur];
    const int sw = (r & 7) << 4;
    bf16x8 kf[4][2], vf[4][2];
#pragma unroll
    for (int tt = 0; tt < 4; ++tt) {
      const int rowb = (tt * 16 + r) * 128;
#pragma unroll
      for (int kk = 0; kk < 2; ++kk) {
        const int cb = (kk * 64 + g * 16) ^ sw;
        kf[tt][kk] = *(const bf16x8*)(KsT + rowb + cb);
        vf[tt][kk] = *(const bf16x8*)(VsT + rowb + cb);
      }
    }

#pragma unroll
    for (int mi = 0; mi < 2; ++mi) {
      const int qbm = qb[mi];
      if (t * 64 > qbm + 15) continue;

      f32x4 sT[4];
#pragma unroll
      for (int tt = 0; tt < 4; ++tt) {
        f32x4 a = {0.f, 0.f, 0.f, 0.f};
        a = __builtin_amdgcn_mfma_f32_16x16x32_bf16(kf[tt][0], qf[mi][0], a, 0, 0, 0);
        a = __builtin_amdgcn_mfma_f32_16x16x32_bf16(kf[tt][1], qf[mi][1], a, 0, 0, 0);
        sT[tt] = a;
      }
      const int qg = qbm + qi;
      float mx = -__builtin_inff();
#pragma unroll
      for (int tt = 0; tt < 4; ++tt)
#pragma unroll
        for (int j = 0; j < 4; ++j) {
          const int kv = t * 64 + tt * 16 + 4 * g + j;
          float sv = sT[tt][j] * 0.125f;
          sv = (kv <= qg) ? sv : -__builtin_inff();
          sT[tt][j] = sv;
          mx = fmaxf(mx, sv);
        }
      mx = fmaxf(mx, __shfl_xor(mx, 16));
      mx = fmaxf(mx, __shfl_xor(mx, 32));
      const float mnew = fmaxf(m_[mi], mx);
      const float rs = __expf(m_[mi] - mnew);
      m_[mi] = mnew;
      float ts = 0.f;
#pragma unroll
      for (int tt = 0; tt < 4; ++tt)
#pragma unroll
        for (int j = 0; j < 4; ++j) {
          const float p = __expf(sT[tt][j] - mnew);
          sT[tt][j] = p;
          ts += p;
        }
      ts += __shfl_xor(ts, 16);
      ts += __shfl_xor(ts, 32);
      l_[mi] = l_[mi] * rs + ts;

#pragma unroll
      for (int tt = 0; tt < 4; ++tt) {
        uint2 wq;
        wq.x = pk2(sT[tt][0], sT[tt][1]);
        wq.y = pk2(sT[tt][2], sT[tt][3]);
        *(uint2*)&Pl[wv][r][tt * 16 + 4 * g] = wq;
      }
      asm volatile("s_waitcnt lgkmcnt(0)" ::: "memory");

      float rsb[4];
#pragma unroll
      for (int j = 0; j < 4; ++j) rsb[j] = __shfl(rs, 4 * g + j);
#pragma unroll
      for (int df = 0; df < 4; ++df)
#pragma unroll
        for (int j = 0; j < 4; ++j) oacc[mi][df][j] *= rsb[j];

#pragma unroll
      for (int kk = 0; kk < 2; ++kk) {
        const bf16x8 pa = *(const bf16x8*)&Pl[wv][r][kk * 32 + g * 8];
#pragma unroll
        for (int df = 0; df < 4; ++df)
          oacc[mi][df] = __builtin_amdgcn_mfma_f32_16x16x32_bf16(pa, vf[df][kk], oacc[mi][df], 0, 0, 0);
      }
    }
    __syncthreads();
  }
#undef ASTAGE

  // write concat layout [B,T,1024], K-swizzled for O-proj A-operand
  const int b = bh >> 4, h = bh & 15;
#pragma unroll
  for (int mi = 0; mi < 2; ++mi) {
    float lb[4];
#pragma unroll
    for (int j = 0; j < 4; ++j) lb[j] = __shfl(l_[mi], 4 * g + j);
#pragma unroll
    for (int df = 0; df < 4; ++df)
#pragma unroll
      for (int j = 0; j < 4; ++j) {
        const int trow = qb[mi] + 4 * g + j;
        const float ov = oacc[mi][df][j] / lb[j];
        const int col = (df * 16 + r) ^ ((trow & 7) << 3);
        Om[((size_t)(b * TSEQ + trow)) * 1024 + h * 64 + col] = f2bf(ov);
      }
  }
}

// ---------------- launch ----------------

extern "C" void kernel_launch(void* const* d_in, const int* in_sizes, int n_in,
                              void* d_out, int out_size, void* d_ws, size_t ws_size,
                              hipStream_t stream) {
  const float* x  = (const float*)d_in[0];
  const float* Wq = (const float*)d_in[1];
  const float* bq = (const float*)d_in[2];
  const float* Wk = (const float*)d_in[3];
  const float* bk = (const float*)d_in[4];
  const float* Wv = (const float*)d_in[5];
  const float* bv = (const float*)d_in[6];
  const float* Wo = (const float*)d_in[7];
  const float* bo = (const float*)d_in[8];
  float* out = (float*)d_out;

  unsigned short* xb  = (unsigned short*)d_ws;               // 8192*1024
  unsigned short* btq = xb + (size_t)8192 * 1024;            // 3072*1024
  unsigned short* wot = btq + (size_t)3072 * 1024;           // 1024*1024
  unsigned short* qb  = wot + (size_t)1024 * 1024;           // 64*2048*64
  unsigned short* kb  = qb + (size_t)64 * 2048 * 64;
  unsigned short* vtb = kb + (size_t)64 * 2048 * 64;

  cast_x_kernel<<<8192, 256, 0, stream>>>((const float4*)x, xb);
  repack_wqkv<<<dim3(16, 16, 3), 256, 0, stream>>>(Wq, Wk, Wv, btq);
  repack_wo<<<dim3(16, 16), 256, 0, stream>>>(Wo, wot);

  // QKV: [8192,1024] x [1024,3072] -> q/k/vT (scattered, attn layouts)
  gemm8<0><<<dim3(32, 12), 512, 0, stream>>>(xb, btq, bq, bk, bv, qb, kb, vtb,
                                             nullptr, 1024, 3072);
  // attention: 16 qp (heavy first) x 64 bh
  attn_fwd<<<1024, 256, 0, stream>>>(qb, kb, vtb, xb);
  // O-proj: [8192,1024] x [1024,1024] -> f32 out
  gemm8<1><<<dim3(32, 4), 512, 0, stream>>>(xb, wot, bo, nullptr, nullptr,
                                            nullptr, nullptr, nullptr, out,
                                            1024, 1024);
}

// Round 4
// 219.202 us; speedup vs baseline: 2.7247x; 1.0760x over previous
//
#include <hip/hip_runtime.h>
#include <stdint.h>

#define TSEQ 2048
#define NHEAD 16

typedef __attribute__((ext_vector_type(8))) short bf16x8;
typedef __attribute__((ext_vector_type(4))) float f32x4;

__device__ __forceinline__ unsigned short f2bf(float f) {
  union { float f; uint32_t u; } c;
  c.f = f;
  uint32_t u = c.u;
  u += 0x7fffu + ((u >> 16) & 1u);   // round-nearest-even
  return (unsigned short)(u >> 16);
}

__device__ __forceinline__ uint32_t pk2(float a, float b) {
  return (uint32_t)f2bf(a) | ((uint32_t)f2bf(b) << 16);
}

using as3_void  = __attribute__((address_space(3))) void;
using as1_cvoid = const __attribute__((address_space(1))) void;

__device__ __forceinline__ void gld_lds16(const void* g, void* l) {
  // async global->LDS, 16B/lane; LDS dest = wave-uniform base + lane*16
  __builtin_amdgcn_global_load_lds((as1_cvoid*)g, (as3_void*)l, 16, 0, 0);
}

// ---------------- prep kernels (produce K-swizzled global layouts) ----------------
// GEMM operand layout: X'[row][k] = X[row][k ^ ((row&7)<<3)] within each 64-elem k-block.
// gld_lds fills LDS linearly; ds_read applies the same XOR -> bank-balanced (verified 0 conflicts R3).

__global__ void cast_x_kernel(const float4* __restrict__ x, unsigned short* __restrict__ xb) {
  int i = blockIdx.x * 256 + threadIdx.x;   // group of 4 elems
  float4 v = x[i];
  int e = i * 4;
  int m = e >> 10, k = e & 1023;
  int ks = k ^ ((m & 7) << 3);
  ushort4 o;
  o.x = f2bf(v.x); o.y = f2bf(v.y); o.z = f2bf(v.z); o.w = f2bf(v.w);
  *(ushort4*)(xb + (size_t)m * 1024 + ks) = o;
}

// Wq/Wk/Wv [H,C,HD] f32 -> BT[(which*1024 + h*64 + d)][c ^ swz(d)] bf16
__global__ void repack_wqkv(const float* __restrict__ Wq, const float* __restrict__ Wk,
                            const float* __restrict__ Wv, unsigned short* __restrict__ BT) {
  __shared__ unsigned short tile[64][72];
  const float* W = (blockIdx.z == 0) ? Wq : (blockIdx.z == 1) ? Wk : Wv;
  const int h = blockIdx.y;
  const int c0 = blockIdx.x * 64;
  const int t = threadIdx.x;
  const float* src = W + ((size_t)h * 1024 + c0) * 64;
#pragma unroll
  for (int p = 0; p < 16; ++p) {
    int idx = p * 256 + t;
    int cc = idx >> 6, d = idx & 63;
    tile[cc][d] = f2bf(src[(size_t)cc * 64 + d]);
  }
  __syncthreads();
  unsigned short* dst = BT + ((size_t)blockIdx.z * 1024 + (size_t)h * 64) * 1024 + c0;
#pragma unroll
  for (int p = 0; p < 16; ++p) {
    int idx = p * 256 + t;
    int d = idx >> 6, cc = idx & 63;
    dst[(size_t)d * 1024 + (cc ^ ((d & 7) << 3))] = tile[cc][d];
  }
}

// Wo [C,C] f32 -> WoT[n][k ^ swz(n)] bf16 (transpose + swizzle)
__global__ void repack_wo(const float* __restrict__ Wo, unsigned short* __restrict__ WoT) {
  __shared__ unsigned short tile[64][72];
  const int k0 = blockIdx.x * 64;
  const int n0 = blockIdx.y * 64;
  const int t = threadIdx.x;
#pragma unroll
  for (int p = 0; p < 16; ++p) {
    int idx = p * 256 + t;
    int kk = idx >> 6, nn = idx & 63;
    tile[kk][nn] = f2bf(Wo[(size_t)(k0 + kk) * 1024 + n0 + nn]);
  }
  __syncthreads();
#pragma unroll
  for (int p = 0; p < 16; ++p) {
    int idx = p * 256 + t;
    int nn = idx >> 6, kk = idx & 63;
    WoT[(size_t)(n0 + nn) * 1024 + k0 + (kk ^ ((nn & 7) << 3))] = tile[kk][nn];
  }
}

// ---------------- GEMM: C = A[M,K] * BT[N,K]^T + bias ----------------
// m97 structure: 128x128 tile, BK=64, 4 waves (2x2), 4x4 16x16x32 frags/wave,
// global_load_lds width-16 staging, K-swizzled operands (0 bank conflicts).
// Epilogue: LDS-bounce re-layout -> fully coalesced b128 global stores.
// MODE 0: QKV -> q [bh][t][d], k [bh][t][d^swz(t)], vT [bh][t/64][d][t%64^swz(d)]
// MODE 1: f32 out + bias.

template <int MODE>
__global__ __launch_bounds__(256) void gemm_bt(
    const unsigned short* __restrict__ A, const unsigned short* __restrict__ BTm,
    const float* __restrict__ bias0, const float* __restrict__ bias1,
    const float* __restrict__ bias2,
    unsigned short* __restrict__ qo, unsigned short* __restrict__ ko,
    unsigned short* __restrict__ vto, float* __restrict__ outf,
    int K, int N) {
  __shared__ __align__(16) char lds[(MODE == 1) ? 36864 : 32768];
  unsigned short* As = (unsigned short*)lds;
  unsigned short* Bs = (unsigned short*)(lds + 16384);

  const int tid = threadIdx.x, lane = tid & 63, wv = tid >> 6;
  const int wr = wv >> 1, wc = wv & 1;
  const int g = lane >> 4, r = lane & 15;
  const int m0 = blockIdx.x * 128, n0 = blockIdx.y * 128;
  const int xr = (r & 7) << 4;

  f32x4 acc[4][4] = {};

  const int arow = tid >> 3;            // 0..31
  const int acol = (tid & 7) * 8;       // 0..56
  const unsigned short* Ab = A + (size_t)(m0 + arow) * K + acol;
  const unsigned short* Bb = BTm + (size_t)(n0 + arow) * K + acol;
  char* AsB = (char*)As + wv * 1024;
  char* BsB = (char*)Bs + wv * 1024;

  for (int k0 = 0; k0 < K; k0 += 64) {
#pragma unroll
    for (int i = 0; i < 4; ++i) {
      gld_lds16(Ab + (size_t)i * 32 * K + k0, AsB + i * 4096);
      gld_lds16(Bb + (size_t)i * 32 * K + k0, BsB + i * 4096);
    }
    __syncthreads();
    const char* Ar = (const char*)As;
    const char* Br = (const char*)Bs;
#pragma unroll
    for (int kk = 0; kk < 2; ++kk) {
      bf16x8 af[4], bfv[4];
#pragma unroll
      for (int f = 0; f < 4; ++f) {
        af[f]  = *(const bf16x8*)(Ar + (wr * 64 + f * 16 + r) * 128 + ((kk * 64 + g * 16) ^ xr));
        bfv[f] = *(const bf16x8*)(Br + (wc * 64 + f * 16 + r) * 128 + ((kk * 64 + g * 16) ^ xr));
      }
#pragma unroll
      for (int fm = 0; fm < 4; ++fm)
#pragma unroll
        for (int fn = 0; fn < 4; ++fn)
          acc[fm][fn] = __builtin_amdgcn_mfma_f32_16x16x32_bf16(af[fm], bfv[fn], acc[fm][fn], 0, 0, 0);
    }
    __syncthreads();
  }

  // ---------------- LDS-bounce epilogue: coalesced stores ----------------
  if (MODE == 0) {
    const int which = n0 >> 10;  // 0=q 1=k 2=v (uniform per block)
    const float* bias = (which == 0) ? bias0 : (which == 1) ? bias1 : bias2;
    const int b = m0 >> 11;
    const int t0 = m0 & 2047;
    unsigned short* ep = (unsigned short*)lds;

#pragma unroll
    for (int h = 0; h < 2; ++h) {   // 64-col half == one head's d-range
      const int head = ((n0 & 1023) + h * 64) >> 6;
      const size_t bhb = (size_t)(b * NHEAD + head) * 131072;
      __syncthreads();
      if (wc == h) {
        if (which == 2) {
          // transposed tile: ep[d][t], pitch 136 elems (272B, 16B-aligned rows)
#pragma unroll
          for (int fn = 0; fn < 4; ++fn) {
            const int d = fn * 16 + r;
            const float bvl = bias[head * 64 + d];
#pragma unroll
            for (int fm = 0; fm < 4; ++fm)
#pragma unroll
              for (int j = 0; j < 4; ++j) {
                const int t = wr * 64 + fm * 16 + 4 * g + j;
                ep[d * 136 + t] = f2bf(acc[fm][fn][j] + bvl);
              }
          }
        } else {
          // tile: ep[t][d], pitch 72 elems (144B, 16B-aligned rows)
#pragma unroll
          for (int fn = 0; fn < 4; ++fn) {
            const int d = fn * 16 + r;
            const float bvl = bias[head * 64 + d];
#pragma unroll
            for (int fm = 0; fm < 4; ++fm)
#pragma unroll
              for (int j = 0; j < 4; ++j) {
                const int t = wr * 64 + fm * 16 + 4 * g + j;
                ep[t * 72 + d] = f2bf(acc[fm][fn][j] + bvl);
              }
          }
        }
      }
      __syncthreads();
      if (which == 2) {
        // store 64 d-rows x 128 t: 16 lanes/row, 4 passes
#pragma unroll
        for (int p = 0; p < 4; ++p) {
          const int d = p * 16 + (tid >> 4);
          const int seg = tid & 15;
          const bf16x8 v8 = *(const bf16x8*)(ep + d * 136 + seg * 8);
          const int tt = t0 + seg * 8;
          *(bf16x8*)(vto + bhb + (size_t)(tt >> 6) * 4096 + (size_t)d * 64 +
                     ((tt & 63) ^ ((d & 7) << 3))) = v8;
        }
      } else {
        unsigned short* qk = (which == 1) ? ko : qo;
        // store 128 t-rows x 64 d: 8 lanes/row, 4 passes
#pragma unroll
        for (int p = 0; p < 4; ++p) {
          const int row = p * 32 + (tid >> 3);
          const int seg = tid & 7;
          const bf16x8 v8 = *(const bf16x8*)(ep + row * 72 + seg * 8);
          const int tt = t0 + row;
          int dbase = seg * 8;
          if (which == 1) dbase ^= (tt & 7) << 3;
          *(bf16x8*)(qk + bhb + (size_t)tt * 64 + dbase) = v8;
        }
      }
    }
  } else {
    float* epf = (float*)lds;   // [128][68 f32] pitch 272B
#pragma unroll
    for (int h = 0; h < 2; ++h) {
      __syncthreads();
      if (wc == h) {
#pragma unroll
        for (int fn = 0; fn < 4; ++fn) {
          const int n = n0 + h * 64 + fn * 16 + r;
          const float bvl = bias0[n];
#pragma unroll
          for (int fm = 0; fm < 4; ++fm)
#pragma unroll
            for (int j = 0; j < 4; ++j)
              epf[(wr * 64 + fm * 16 + 4 * g + j) * 68 + fn * 16 + r] = acc[fm][fn][j] + bvl;
        }
      }
      __syncthreads();
#pragma unroll
      for (int p = 0; p < 8; ++p) {
        const int row = p * 16 + (tid >> 4);
        const int seg = tid & 15;
        const f32x4 v4 = *(const f32x4*)(epf + row * 68 + seg * 4);
        *(f32x4*)(outf + (size_t)(m0 + row) * N + n0 + h * 64 + seg * 4) = v4;
      }
    }
  }
}

// ---------------- flash attention (causal), LDS-staged, swapped QK^T ----------------
// (unchanged from round 3 — validated)

__global__ __launch_bounds__(256) void attn_fwd(const unsigned short* __restrict__ Qm,
                                                const unsigned short* __restrict__ Km,
                                                const unsigned short* __restrict__ Vtm,
                                                unsigned short* __restrict__ Om) {
  __shared__ __align__(16) unsigned short Ks[2][4096];
  __shared__ __align__(16) unsigned short Vs[2][4096];
  __shared__ __align__(16) unsigned short Pl[4][16][72];

  const int tid = threadIdx.x, lane = tid & 63, wv = tid >> 6;
  const int g = lane >> 4, r = lane & 15;
  const int bh = blockIdx.x & 63;
  const int qp = 15 - (blockIdx.x >> 6);      // heavy blocks dispatch first

  const unsigned short* Qp = Qm + (size_t)bh * 131072;
  const unsigned short* Kp = Km + (size_t)bh * 131072;
  const unsigned short* Vp = Vtm + (size_t)bh * 131072;

  const int qb[2] = {qp * 128 + wv * 16, qp * 128 + 64 + wv * 16};

  bf16x8 qf[2][2];
#pragma unroll
  for (int mi = 0; mi < 2; ++mi)
#pragma unroll
    for (int h2 = 0; h2 < 2; ++h2)
      qf[mi][h2] = *(const bf16x8*)(Qp + (size_t)(qb[mi] + r) * 64 + h2 * 32 + g * 8);

  f32x4 oacc[2][4] = {};
  float m_[2] = {-__builtin_inff(), -__builtin_inff()};
  float l_[2] = {0.f, 0.f};
  const int qi = r;

#define ASTAGE(buf, c) do {                                                      \
    const unsigned short* kg_ = Kp + (size_t)(c) * 4096;                         \
    const unsigned short* vg_ = Vp + (size_t)(c) * 4096;                         \
    const int o0_ = wv * 1024;                                                   \
    gld_lds16(kg_ + (o0_ >> 1) + lane * 8, (char*)Ks[buf] + o0_);                \
    gld_lds16(vg_ + (o0_ >> 1) + lane * 8, (char*)Vs[buf] + o0_);                \
    gld_lds16(kg_ + ((o0_ + 4096) >> 1) + lane * 8, (char*)Ks[buf] + o0_ + 4096);\
    gld_lds16(vg_ + ((o0_ + 4096) >> 1) + lane * 8, (char*)Vs[buf] + o0_ + 4096);\
  } while (0)

  const int nt = qp * 2 + 2;
  ASTAGE(0, 0);
  __syncthreads();

  for (int t = 0; t < nt; ++t) {
    const int cur = t & 1;
    if (t + 1 < nt) ASTAGE(cur ^ 1, t + 1);

    const char* KsT = (const char*)Ks[cur];
    const char* VsT = (const char*)Vs[cur];
    const int sw = (r & 7) << 4;
    bf16x8 kf[4][2], vf[4][2];
#pragma unroll
    for (int tt = 0; tt < 4; ++tt) {
      const int rowb = (tt * 16 + r) * 128;
#pragma unroll
      for (int kk = 0; kk < 2; ++kk) {
        const int cb = (kk * 64 + g * 16) ^ sw;
        kf[tt][kk] = *(const bf16x8*)(KsT + rowb + cb);
        vf[tt][kk] = *(const bf16x8*)(VsT + rowb + cb);
      }
    }

#pragma unroll
    for (int mi = 0; mi < 2; ++mi) {
      const int qbm = qb[mi];
      if (t * 64 > qbm + 15) continue;

      f32x4 sT[4];
#pragma unroll
      for (int tt = 0; tt < 4; ++tt) {
        f32x4 a = {0.f, 0.f, 0.f, 0.f};
        a = __builtin_amdgcn_mfma_f32_16x16x32_bf16(kf[tt][0], qf[mi][0], a, 0, 0, 0);
        a = __builtin_amdgcn_mfma_f32_16x16x32_bf16(kf[tt][1], qf[mi][1], a, 0, 0, 0);
        sT[tt] = a;
      }
      const int qg = qbm + qi;
      float mx = -__builtin_inff();
#pragma unroll
      for (int tt = 0; tt < 4; ++tt)
#pragma unroll
        for (int j = 0; j < 4; ++j) {
          const int kv = t * 64 + tt * 16 + 4 * g + j;
          float sv = sT[tt][j] * 0.125f;
          sv = (kv <= qg) ? sv : -__builtin_inff();
          sT[tt][j] = sv;
          mx = fmaxf(mx, sv);
        }
      mx = fmaxf(mx, __shfl_xor(mx, 16));
      mx = fmaxf(mx, __shfl_xor(mx, 32));
      const float mnew = fmaxf(m_[mi], mx);
      const float rs = __expf(m_[mi] - mnew);
      m_[mi] = mnew;
      float ts = 0.f;
#pragma unroll
      for (int tt = 0; tt < 4; ++tt)
#pragma unroll
        for (int j = 0; j < 4; ++j) {
          const float p = __expf(sT[tt][j] - mnew);
          sT[tt][j] = p;
          ts += p;
        }
      ts += __shfl_xor(ts, 16);
      ts += __shfl_xor(ts, 32);
      l_[mi] = l_[mi] * rs + ts;

#pragma unroll
      for (int tt = 0; tt < 4; ++tt) {
        uint2 wq;
        wq.x = pk2(sT[tt][0], sT[tt][1]);
        wq.y = pk2(sT[tt][2], sT[tt][3]);
        *(uint2*)&Pl[wv][r][tt * 16 + 4 * g] = wq;
      }
      asm volatile("s_waitcnt lgkmcnt(0)" ::: "memory");

      float rsb[4];
#pragma unroll
      for (int j = 0; j < 4; ++j) rsb[j] = __shfl(rs, 4 * g + j);
#pragma unroll
      for (int df = 0; df < 4; ++df)
#pragma unroll
        for (int j = 0; j < 4; ++j) oacc[mi][df][j] *= rsb[j];

#pragma unroll
      for (int kk = 0; kk < 2; ++kk) {
        const bf16x8 pa = *(const bf16x8*)&Pl[wv][r][kk * 32 + g * 8];
#pragma unroll
        for (int df = 0; df < 4; ++df)
          oacc[mi][df] = __builtin_amdgcn_mfma_f32_16x16x32_bf16(pa, vf[df][kk], oacc[mi][df], 0, 0, 0);
      }
    }
    __syncthreads();
  }
#undef ASTAGE

  // write concat layout [B,T,1024], K-swizzled for O-proj A-operand
  const int b = bh >> 4, h = bh & 15;
#pragma unroll
  for (int mi = 0; mi < 2; ++mi) {
    float lb[4];
#pragma unroll
    for (int j = 0; j < 4; ++j) lb[j] = __shfl(l_[mi], 4 * g + j);
#pragma unroll
    for (int df = 0; df < 4; ++df)
#pragma unroll
      for (int j = 0; j < 4; ++j) {
        const int trow = qb[mi] + 4 * g + j;
        const float ov = oacc[mi][df][j] / lb[j];
        const int col = (df * 16 + r) ^ ((trow & 7) << 3);
        Om[((size_t)(b * TSEQ + trow)) * 1024 + h * 64 + col] = f2bf(ov);
      }
  }
}

// ---------------- launch ----------------

extern "C" void kernel_launch(void* const* d_in, const int* in_sizes, int n_in,
                              void* d_out, int out_size, void* d_ws, size_t ws_size,
                              hipStream_t stream) {
  const float* x  = (const float*)d_in[0];
  const float* Wq = (const float*)d_in[1];
  const float* bq = (const float*)d_in[2];
  const float* Wk = (const float*)d_in[3];
  const float* bk = (const float*)d_in[4];
  const float* Wv = (const float*)d_in[5];
  const float* bv = (const float*)d_in[6];
  const float* Wo = (const float*)d_in[7];
  const float* bo = (const float*)d_in[8];
  float* out = (float*)d_out;

  unsigned short* xb  = (unsigned short*)d_ws;               // 8192*1024
  unsigned short* btq = xb + (size_t)8192 * 1024;            // 3072*1024
  unsigned short* wot = btq + (size_t)3072 * 1024;           // 1024*1024
  unsigned short* qb  = wot + (size_t)1024 * 1024;           // 64*2048*64
  unsigned short* kb  = qb + (size_t)64 * 2048 * 64;
  unsigned short* vtb = kb + (size_t)64 * 2048 * 64;

  cast_x_kernel<<<8192, 256, 0, stream>>>((const float4*)x, xb);
  repack_wqkv<<<dim3(16, 16, 3), 256, 0, stream>>>(Wq, Wk, Wv, btq);
  repack_wo<<<dim3(16, 16), 256, 0, stream>>>(Wo, wot);

  // QKV: [8192,1024] x [1024,3072] -> q/k/vT (attn layouts)
  gemm_bt<0><<<dim3(64, 24), 256, 0, stream>>>(xb, btq, bq, bk, bv, qb, kb, vtb,
                                               nullptr, 1024, 3072);
  // attention: 16 qp (heavy first) x 64 bh
  attn_fwd<<<1024, 256, 0, stream>>>(qb, kb, vtb, xb);
  // O-proj: [8192,1024] x [1024,1024] -> f32 out
  gemm_bt<1><<<dim3(64, 8), 256, 0, stream>>>(xb, wot, bo, nullptr, nullptr,
                                              nullptr, nullptr, nullptr, out,
                                              1024, 1024);
}

// Round 5
// 197.509 us; speedup vs baseline: 3.0239x; 1.1098x over previous
//
#include <hip/hip_runtime.h>
#include <stdint.h>

#define TSEQ 2048
#define NHEAD 16

typedef __attribute__((ext_vector_type(8))) short bf16x8;
typedef __attribute__((ext_vector_type(4))) short bf16x4;
typedef __attribute__((ext_vector_type(4))) float f32x4;

__device__ __forceinline__ unsigned short f2bf(float f) {
  union { float f; uint32_t u; } c;
  c.f = f;
  uint32_t u = c.u;
  u += 0x7fffu + ((u >> 16) & 1u);   // round-nearest-even
  return (unsigned short)(u >> 16);
}

using as3_void  = __attribute__((address_space(3))) void;
using as1_cvoid = const __attribute__((address_space(1))) void;

__device__ __forceinline__ void gld_lds16(const void* g, void* l) {
  // async global->LDS, 16B/lane; LDS dest = wave-uniform base + lane*16
  __builtin_amdgcn_global_load_lds((as1_cvoid*)g, (as3_void*)l, 16, 0, 0);
}

// ---------------- prep kernels (produce K-swizzled global layouts) ----------------
// GEMM operand layout: X'[row][k] = X[row][k ^ ((row&7)<<3)] within each 64-elem k-block.
// gld_lds fills LDS linearly; ds_read applies the same XOR -> bank-balanced (0 conflicts, R3).

__global__ void cast_x_kernel(const float4* __restrict__ x, unsigned short* __restrict__ xb) {
  int i = blockIdx.x * 256 + threadIdx.x;   // group of 4 elems
  float4 v = x[i];
  int e = i * 4;
  int m = e >> 10, k = e & 1023;
  int ks = k ^ ((m & 7) << 3);
  ushort4 o;
  o.x = f2bf(v.x); o.y = f2bf(v.y); o.z = f2bf(v.z); o.w = f2bf(v.w);
  *(ushort4*)(xb + (size_t)m * 1024 + ks) = o;
}

// Wq/Wk/Wv [H,C,HD] f32 -> BT[(which*1024 + h*64 + d)][c ^ swz(d)] bf16
__global__ void repack_wqkv(const float* __restrict__ Wq, const float* __restrict__ Wk,
                            const float* __restrict__ Wv, unsigned short* __restrict__ BT) {
  __shared__ unsigned short tile[64][72];
  const float* W = (blockIdx.z == 0) ? Wq : (blockIdx.z == 1) ? Wk : Wv;
  const int h = blockIdx.y;
  const int c0 = blockIdx.x * 64;
  const int t = threadIdx.x;
  const float* src = W + ((size_t)h * 1024 + c0) * 64;
#pragma unroll
  for (int p = 0; p < 16; ++p) {
    int idx = p * 256 + t;
    int cc = idx >> 6, d = idx & 63;
    tile[cc][d] = f2bf(src[(size_t)cc * 64 + d]);
  }
  __syncthreads();
  unsigned short* dst = BT + ((size_t)blockIdx.z * 1024 + (size_t)h * 64) * 1024 + c0;
#pragma unroll
  for (int p = 0; p < 16; ++p) {
    int idx = p * 256 + t;
    int d = idx >> 6, cc = idx & 63;
    dst[(size_t)d * 1024 + (cc ^ ((d & 7) << 3))] = tile[cc][d];
  }
}

// Wo [C,C] f32 -> WoT[n][k ^ swz(n)] bf16 (transpose + swizzle)
__global__ void repack_wo(const float* __restrict__ Wo, unsigned short* __restrict__ WoT) {
  __shared__ unsigned short tile[64][72];
  const int k0 = blockIdx.x * 64;
  const int n0 = blockIdx.y * 64;
  const int t = threadIdx.x;
#pragma unroll
  for (int p = 0; p < 16; ++p) {
    int idx = p * 256 + t;
    int kk = idx >> 6, nn = idx & 63;
    tile[kk][nn] = f2bf(Wo[(size_t)(k0 + kk) * 1024 + n0 + nn]);
  }
  __syncthreads();
#pragma unroll
  for (int p = 0; p < 16; ++p) {
    int idx = p * 256 + t;
    int nn = idx >> 6, kk = idx & 63;
    WoT[(size_t)(n0 + nn) * 1024 + k0 + (kk ^ ((nn & 7) << 3))] = tile[kk][nn];
  }
}

// ---------------- GEMM: C = A[M,K] * BT[N,K]^T + bias ----------------
// m97 structure: 128x128 tile, BK=64, 4 waves (2x2), 4x4 16x16x32 frags/wave,
// global_load_lds width-16 staging, K-swizzled operands, LDS-bounce epilogue.
// MODE 0: QKV -> q [bh][t][d], k [bh][t][d^swz(t)],
//         vT [bh][t/64][d][ rot(t%64) ^ swz(d) ]  where rot places t-value at
//         slot q: q[5]=t[5], q[4:3]=t[3:2], q[2]=t[4], q[1:0]=t[1:0]
//         (matches attn's in-register P fragment permutation — see attn_fwd).
// MODE 1: f32 out + bias.

template <int MODE>
__global__ __launch_bounds__(256) void gemm_bt(
    const unsigned short* __restrict__ A, const unsigned short* __restrict__ BTm,
    const float* __restrict__ bias0, const float* __restrict__ bias1,
    const float* __restrict__ bias2,
    unsigned short* __restrict__ qo, unsigned short* __restrict__ ko,
    unsigned short* __restrict__ vto, float* __restrict__ outf,
    int K, int N) {
  __shared__ __align__(16) char lds[(MODE == 1) ? 36864 : 32768];
  unsigned short* As = (unsigned short*)lds;
  unsigned short* Bs = (unsigned short*)(lds + 16384);

  const int tid = threadIdx.x, lane = tid & 63, wv = tid >> 6;
  const int wr = wv >> 1, wc = wv & 1;
  const int g = lane >> 4, r = lane & 15;
  const int m0 = blockIdx.x * 128, n0 = blockIdx.y * 128;
  const int xr = (r & 7) << 4;

  f32x4 acc[4][4] = {};

  const int arow = tid >> 3;            // 0..31
  const int acol = (tid & 7) * 8;       // 0..56
  const unsigned short* Ab = A + (size_t)(m0 + arow) * K + acol;
  const unsigned short* Bb = BTm + (size_t)(n0 + arow) * K + acol;
  char* AsB = (char*)As + wv * 1024;
  char* BsB = (char*)Bs + wv * 1024;

  for (int k0 = 0; k0 < K; k0 += 64) {
#pragma unroll
    for (int i = 0; i < 4; ++i) {
      gld_lds16(Ab + (size_t)i * 32 * K + k0, AsB + i * 4096);
      gld_lds16(Bb + (size_t)i * 32 * K + k0, BsB + i * 4096);
    }
    __syncthreads();
    const char* Ar = (const char*)As;
    const char* Br = (const char*)Bs;
#pragma unroll
    for (int kk = 0; kk < 2; ++kk) {
      bf16x8 af[4], bfv[4];
#pragma unroll
      for (int f = 0; f < 4; ++f) {
        af[f]  = *(const bf16x8*)(Ar + (wr * 64 + f * 16 + r) * 128 + ((kk * 64 + g * 16) ^ xr));
        bfv[f] = *(const bf16x8*)(Br + (wc * 64 + f * 16 + r) * 128 + ((kk * 64 + g * 16) ^ xr));
      }
#pragma unroll
      for (int fm = 0; fm < 4; ++fm)
#pragma unroll
        for (int fn = 0; fn < 4; ++fn)
          acc[fm][fn] = __builtin_amdgcn_mfma_f32_16x16x32_bf16(af[fm], bfv[fn], acc[fm][fn], 0, 0, 0);
    }
    __syncthreads();
  }

  // ---------------- LDS-bounce epilogue: coalesced stores ----------------
  if (MODE == 0) {
    const int which = n0 >> 10;  // 0=q 1=k 2=v (uniform per block)
    const float* bias = (which == 0) ? bias0 : (which == 1) ? bias1 : bias2;
    const int b = m0 >> 11;
    const int t0 = m0 & 2047;
    unsigned short* ep = (unsigned short*)lds;

#pragma unroll
    for (int h = 0; h < 2; ++h) {   // 64-col half == one head's d-range
      const int head = ((n0 & 1023) + h * 64) >> 6;
      const size_t bhb = (size_t)(b * NHEAD + head) * 131072;
      __syncthreads();
      if (wc == h) {
        if (which == 2) {
          // transposed tile: ep[d][t], pitch 136 elems (272B, 16B-aligned rows)
#pragma unroll
          for (int fn = 0; fn < 4; ++fn) {
            const int d = fn * 16 + r;
            const float bvl = bias[head * 64 + d];
#pragma unroll
            for (int fm = 0; fm < 4; ++fm)
#pragma unroll
              for (int j = 0; j < 4; ++j) {
                const int t = wr * 64 + fm * 16 + 4 * g + j;
                ep[d * 136 + t] = f2bf(acc[fm][fn][j] + bvl);
              }
          }
        } else {
          // tile: ep[t][d], pitch 72 elems (144B, 16B-aligned rows)
#pragma unroll
          for (int fn = 0; fn < 4; ++fn) {
            const int d = fn * 16 + r;
            const float bvl = bias[head * 64 + d];
#pragma unroll
            for (int fm = 0; fm < 4; ++fm)
#pragma unroll
              for (int j = 0; j < 4; ++j) {
                const int t = wr * 64 + fm * 16 + 4 * g + j;
                ep[t * 72 + d] = f2bf(acc[fm][fn][j] + bvl);
              }
          }
        }
      }
      __syncthreads();
      if (which == 2) {
        // permuted+swizzled V^T store: 16B store = slots q_base..+7;
        // slot q holds t = (q&32) + (q&4)*4 + ((q>>3)&3)*4 + (q&3)
#pragma unroll
        for (int p = 0; p < 4; ++p) {
          const int d = p * 16 + (tid >> 4);
          const int u = tid & 15;
          const int c = u >> 3;          // which 64-t chunk of the 128-t tile
          const int w = u & 7;           // q_base/8: bits [2]=kk, [1:0]=g
          const int kk = w >> 2, gg = w & 3;
          const int base_t = c * 64 + kk * 32 + 4 * gg;
          union { bf16x4 h4[2]; bf16x8 v8; } cc2;
          cc2.h4[0] = *(const bf16x4*)(ep + d * 136 + base_t);        // h=0: j=0..3
          cc2.h4[1] = *(const bf16x4*)(ep + d * 136 + base_t + 16);   // h=1: j=0..3
          const int q_base = w * 8;
          *(bf16x8*)(vto + bhb + (size_t)((t0 >> 6) + c) * 4096 + (size_t)d * 64 +
                     (q_base ^ ((d & 7) << 3))) = cc2.v8;
        }
      } else {
        unsigned short* qk = (which == 1) ? ko : qo;
        // store 128 t-rows x 64 d: 8 lanes/row, 4 passes
#pragma unroll
        for (int p = 0; p < 4; ++p) {
          const int row = p * 32 + (tid >> 3);
          const int seg = tid & 7;
          const bf16x8 v8 = *(const bf16x8*)(ep + row * 72 + seg * 8);
          const int tt = t0 + row;
          int dbase = seg * 8;
          if (which == 1) dbase ^= (tt & 7) << 3;
          *(bf16x8*)(qk + bhb + (size_t)tt * 64 + dbase) = v8;
        }
      }
    }
  } else {
    float* epf = (float*)lds;   // [128][68 f32] pitch 272B
#pragma unroll
    for (int h = 0; h < 2; ++h) {
      __syncthreads();
      if (wc == h) {
#pragma unroll
        for (int fn = 0; fn < 4; ++fn) {
          const int n = n0 + h * 64 + fn * 16 + r;
          const float bvl = bias0[n];
#pragma unroll
          for (int fm = 0; fm < 4; ++fm)
#pragma unroll
            for (int j = 0; j < 4; ++j)
              epf[(wr * 64 + fm * 16 + 4 * g + j) * 68 + fn * 16 + r] = acc[fm][fn][j] + bvl;
        }
      }
      __syncthreads();
#pragma unroll
      for (int p = 0; p < 8; ++p) {
        const int row = p * 16 + (tid >> 4);
        const int seg = tid & 15;
        const f32x4 v4 = *(const f32x4*)(epf + row * 68 + seg * 4);
        *(f32x4*)(outf + (size_t)(m0 + row) * N + n0 + h * 64 + seg * 4) = v4;
      }
    }
  }
}

// ---------------- flash attention (causal) ----------------
// Swapped QK^T (lane owns q=r); P kept IN REGISTERS: the PV contraction axis is
// permuted (slot s=8g+i <-> kv=32kk+16*(i>>2)+4g+(i&3)) so each lane's own
// softmax outputs form its A-fragment after v_cvt_pk_bf16_f32; V's global
// layout (written by gemm epilogue) carries the matching permutation.
// + defer-max (THR=4), uniform-branch causal mask, setprio around MFMA.

__global__ __launch_bounds__(256) void attn_fwd(const unsigned short* __restrict__ Qm,
                                                const unsigned short* __restrict__ Km,
                                                const unsigned short* __restrict__ Vtm,
                                                unsigned short* __restrict__ Om) {
  __shared__ __align__(16) unsigned short Ks[2][4096];
  __shared__ __align__(16) unsigned short Vs[2][4096];

  const int tid = threadIdx.x, lane = tid & 63, wv = tid >> 6;
  const int g = lane >> 4, r = lane & 15;
  const int bh = blockIdx.x & 63;
  const int qp = 15 - (blockIdx.x >> 6);      // heavy blocks dispatch first

  const unsigned short* Qp = Qm + (size_t)bh * 131072;
  const unsigned short* Kp = Km + (size_t)bh * 131072;
  const unsigned short* Vp = Vtm + (size_t)bh * 131072;

  const int qb[2] = {qp * 128 + wv * 16, qp * 128 + 64 + wv * 16};

  bf16x8 qf[2][2];
#pragma unroll
  for (int mi = 0; mi < 2; ++mi)
#pragma unroll
    for (int h2 = 0; h2 < 2; ++h2)
      qf[mi][h2] = *(const bf16x8*)(Qp + (size_t)(qb[mi] + r) * 64 + h2 * 32 + g * 8);

  f32x4 oacc[2][4] = {};
  float m_[2] = {-__builtin_inff(), -__builtin_inff()};
  float l_[2] = {0.f, 0.f};

#define ASTAGE(buf, c) do {                                                      \
    const unsigned short* kg_ = Kp + (size_t)(c) * 4096;                         \
    const unsigned short* vg_ = Vp + (size_t)(c) * 4096;                         \
    const int o0_ = wv * 1024;                                                   \
    gld_lds16(kg_ + (o0_ >> 1) + lane * 8, (char*)Ks[buf] + o0_);                \
    gld_lds16(vg_ + (o0_ >> 1) + lane * 8, (char*)Vs[buf] + o0_);                \
    gld_lds16(kg_ + ((o0_ + 4096) >> 1) + lane * 8, (char*)Ks[buf] + o0_ + 4096);\
    gld_lds16(vg_ + ((o0_ + 4096) >> 1) + lane * 8, (char*)Vs[buf] + o0_ + 4096);\
  } while (0)

  const int nt = qp * 2 + 2;
  ASTAGE(0, 0);
  __syncthreads();

  for (int t = 0; t < nt; ++t) {
    const int cur = t & 1;
    if (t + 1 < nt) ASTAGE(cur ^ 1, t + 1);

    const char* KsT = (const char*)Ks[cur];
    const char* VsT = (const char*)Vs[cur];
    const int sw = (r & 7) << 4;
    bf16x8 kf[4][2], vf[4][2];
#pragma unroll
    for (int tt = 0; tt < 4; ++tt) {
      const int rowb = (tt * 16 + r) * 128;
#pragma unroll
      for (int kk = 0; kk < 2; ++kk) {
        const int cb = (kk * 64 + g * 16) ^ sw;
        kf[tt][kk] = *(const bf16x8*)(KsT + rowb + cb);
        vf[tt][kk] = *(const bf16x8*)(VsT + rowb + cb);
      }
    }

#pragma unroll
    for (int mi = 0; mi < 2; ++mi) {
      const int qbm = qb[mi];
      if (t * 64 > qbm + 15) continue;   // frag fully masked (wave-uniform)

      // S^T[kv][q] = K Q^T : lane holds q = r, kv = 16tt + 4g + j
      f32x4 sT[4];
      __builtin_amdgcn_s_setprio(1);
#pragma unroll
      for (int tt = 0; tt < 4; ++tt) {
        f32x4 a = {0.f, 0.f, 0.f, 0.f};
        a = __builtin_amdgcn_mfma_f32_16x16x32_bf16(kf[tt][0], qf[mi][0], a, 0, 0, 0);
        a = __builtin_amdgcn_mfma_f32_16x16x32_bf16(kf[tt][1], qf[mi][1], a, 0, 0, 0);
        sT[tt] = a;
      }
      __builtin_amdgcn_s_setprio(0);

      const int qg = qbm + r;
      float mx = -__builtin_inff();
      if (t * 64 + 63 > qbm) {           // diagonal tile: per-element mask
#pragma unroll
        for (int tt = 0; tt < 4; ++tt)
#pragma unroll
          for (int j = 0; j < 4; ++j) {
            const int kv = t * 64 + tt * 16 + 4 * g + j;
            float sv = sT[tt][j] * 0.125f;
            sv = (kv <= qg) ? sv : -__builtin_inff();
            sT[tt][j] = sv;
            mx = fmaxf(mx, sv);
          }
      } else {                           // fully visible: no masking
#pragma unroll
        for (int tt = 0; tt < 4; ++tt)
#pragma unroll
          for (int j = 0; j < 4; ++j) {
            const float sv = sT[tt][j] * 0.125f;
            sT[tt][j] = sv;
            mx = fmaxf(mx, sv);
          }
      }
      mx = fmaxf(mx, __shfl_xor(mx, 16));
      mx = fmaxf(mx, __shfl_xor(mx, 32));

      float mcur = m_[mi];
      const bool norescale = __all(mx <= mcur + 4.0f);   // defer-max (T13)
      float rs = 1.f;
      if (!norescale) {
        const float mnew = fmaxf(mcur, mx);
        rs = __expf(mcur - mnew);
        m_[mi] = mnew;
        mcur = mnew;
      }
      float ts = 0.f;
#pragma unroll
      for (int tt = 0; tt < 4; ++tt)
#pragma unroll
        for (int j = 0; j < 4; ++j) {
          const float p = __expf(sT[tt][j] - mcur);
          sT[tt][j] = p;
          ts += p;
        }
      ts += __shfl_xor(ts, 16);
      ts += __shfl_xor(ts, 32);
      if (!norescale) {
        l_[mi] = l_[mi] * rs + ts;
        float rsb[4];
#pragma unroll
        for (int j = 0; j < 4; ++j) rsb[j] = __shfl(rs, 4 * g + j);
#pragma unroll
        for (int df = 0; df < 4; ++df)
#pragma unroll
          for (int j = 0; j < 4; ++j) oacc[mi][df][j] *= rsb[j];
      } else {
        l_[mi] += ts;
      }

      // P -> bf16 A-fragments, fully in-register (permuted contraction axis)
      union { uint32_t w[8]; bf16x8 v[2]; } pu;
#pragma unroll
      for (int tt = 0; tt < 4; ++tt) {
        asm("v_cvt_pk_bf16_f32 %0, %1, %2" : "=v"(pu.w[2 * tt])
            : "v"(sT[tt][0]), "v"(sT[tt][1]));
        asm("v_cvt_pk_bf16_f32 %0, %1, %2" : "=v"(pu.w[2 * tt + 1])
            : "v"(sT[tt][2]), "v"(sT[tt][3]));
      }

      __builtin_amdgcn_s_setprio(1);
#pragma unroll
      for (int kk = 0; kk < 2; ++kk)
#pragma unroll
        for (int df = 0; df < 4; ++df)
          oacc[mi][df] = __builtin_amdgcn_mfma_f32_16x16x32_bf16(pu.v[kk], vf[df][kk], oacc[mi][df], 0, 0, 0);
      __builtin_amdgcn_s_setprio(0);
    }
    __syncthreads();
  }
#undef ASTAGE

  // write concat layout [B,T,1024], K-swizzled for O-proj A-operand
  const int b = bh >> 4, h = bh & 15;
#pragma unroll
  for (int mi = 0; mi < 2; ++mi) {
    float lb[4];
#pragma unroll
    for (int j = 0; j < 4; ++j) lb[j] = __shfl(l_[mi], 4 * g + j);
#pragma unroll
    for (int df = 0; df < 4; ++df)
#pragma unroll
      for (int j = 0; j < 4; ++j) {
        const int trow = qb[mi] + 4 * g + j;
        const float ov = oacc[mi][df][j] / lb[j];
        const int col = (df * 16 + r) ^ ((trow & 7) << 3);
        Om[((size_t)(b * TSEQ + trow)) * 1024 + h * 64 + col] = f2bf(ov);
      }
  }
}

// ---------------- launch ----------------

extern "C" void kernel_launch(void* const* d_in, const int* in_sizes, int n_in,
                              void* d_out, int out_size, void* d_ws, size_t ws_size,
                              hipStream_t stream) {
  const float* x  = (const float*)d_in[0];
  const float* Wq = (const float*)d_in[1];
  const float* bq = (const float*)d_in[2];
  const float* Wk = (const float*)d_in[3];
  const float* bk = (const float*)d_in[4];
  const float* Wv = (const float*)d_in[5];
  const float* bv = (const float*)d_in[6];
  const float* Wo = (const float*)d_in[7];
  const float* bo = (const float*)d_in[8];
  float* out = (float*)d_out;

  unsigned short* xb  = (unsigned short*)d_ws;               // 8192*1024
  unsigned short* btq = xb + (size_t)8192 * 1024;            // 3072*1024
  unsigned short* wot = btq + (size_t)3072 * 1024;           // 1024*1024
  unsigned short* qb  = wot + (size_t)1024 * 1024;           // 64*2048*64
  unsigned short* kb  = qb + (size_t)64 * 2048 * 64;
  unsigned short* vtb = kb + (size_t)64 * 2048 * 64;

  cast_x_kernel<<<8192, 256, 0, stream>>>((const float4*)x, xb);
  repack_wqkv<<<dim3(16, 16, 3), 256, 0, stream>>>(Wq, Wk, Wv, btq);
  repack_wo<<<dim3(16, 16), 256, 0, stream>>>(Wo, wot);

  // QKV: [8192,1024] x [1024,3072] -> q/k/vT (attn layouts)
  gemm_bt<0><<<dim3(64, 24), 256, 0, stream>>>(xb, btq, bq, bk, bv, qb, kb, vtb,
                                               nullptr, 1024, 3072);
  // attention: 16 qp (heavy first) x 64 bh
  attn_fwd<<<1024, 256, 0, stream>>>(qb, kb, vtb, xb);
  // O-proj: [8192,1024] x [1024,1024] -> f32 out
  gemm_bt<1><<<dim3(64, 8), 256, 0, stream>>>(xb, wot, bo, nullptr, nullptr,
                                              nullptr, nullptr, nullptr, out,
                                              1024, 1024);
}

// Round 6
// 181.839 us; speedup vs baseline: 3.2845x; 1.0862x over previous
//
#include <hip/hip_runtime.h>
#include <stdint.h>

#define TSEQ 2048
#define NHEAD 16

typedef __attribute__((ext_vector_type(8))) short bf16x8;
typedef __attribute__((ext_vector_type(4))) short bf16x4;
typedef __attribute__((ext_vector_type(4))) float f32x4;

__device__ __forceinline__ unsigned short f2bf(float f) {
  union { float f; uint32_t u; } c;
  c.f = f;
  uint32_t u = c.u;
  u += 0x7fffu + ((u >> 16) & 1u);   // round-nearest-even
  return (unsigned short)(u >> 16);
}

__device__ __forceinline__ float fexp2(float x) {
#if __has_builtin(__builtin_amdgcn_exp2f)
  return __builtin_amdgcn_exp2f(x);
#else
  return __builtin_exp2f(x);
#endif
}

using as3_void  = __attribute__((address_space(3))) void;
using as1_cvoid = const __attribute__((address_space(1))) void;

__device__ __forceinline__ void gld_lds16(const void* g, void* l) {
  // async global->LDS, 16B/lane; LDS dest = wave-uniform base + lane*16
  __builtin_amdgcn_global_load_lds((as1_cvoid*)g, (as3_void*)l, 16, 0, 0);
}

// ---------------- prep kernels (produce K-swizzled global layouts) ----------------
// GEMM operand layout: X'[row][k] = X[row][k ^ ((row&7)<<3)] within each 64-elem k-block.
// gld_lds fills LDS linearly; ds_read applies the same XOR -> bank-balanced (0 conflicts, R3).

__global__ void cast_x_kernel(const float4* __restrict__ x, unsigned short* __restrict__ xb) {
  int i = blockIdx.x * 256 + threadIdx.x;   // group of 4 elems
  float4 v = x[i];
  int e = i * 4;
  int m = e >> 10, k = e & 1023;
  int ks = k ^ ((m & 7) << 3);
  ushort4 o;
  o.x = f2bf(v.x); o.y = f2bf(v.y); o.z = f2bf(v.z); o.w = f2bf(v.w);
  *(ushort4*)(xb + (size_t)m * 1024 + ks) = o;
}

// Wq/Wk/Wv [H,C,HD] f32 -> BT[(which*1024 + h*64 + d)][c ^ swz(d)] bf16
__global__ void repack_wqkv(const float* __restrict__ Wq, const float* __restrict__ Wk,
                            const float* __restrict__ Wv, unsigned short* __restrict__ BT) {
  __shared__ unsigned short tile[64][72];
  const float* W = (blockIdx.z == 0) ? Wq : (blockIdx.z == 1) ? Wk : Wv;
  const int h = blockIdx.y;
  const int c0 = blockIdx.x * 64;
  const int t = threadIdx.x;
  const float* src = W + ((size_t)h * 1024 + c0) * 64;
#pragma unroll
  for (int p = 0; p < 16; ++p) {
    int idx = p * 256 + t;
    int cc = idx >> 6, d = idx & 63;
    tile[cc][d] = f2bf(src[(size_t)cc * 64 + d]);
  }
  __syncthreads();
  unsigned short* dst = BT + ((size_t)blockIdx.z * 1024 + (size_t)h * 64) * 1024 + c0;
#pragma unroll
  for (int p = 0; p < 16; ++p) {
    int idx = p * 256 + t;
    int d = idx >> 6, cc = idx & 63;
    dst[(size_t)d * 1024 + (cc ^ ((d & 7) << 3))] = tile[cc][d];
  }
}

// Wo [C,C] f32 -> WoT[n][k ^ swz(n)] bf16 (transpose + swizzle)
__global__ void repack_wo(const float* __restrict__ Wo, unsigned short* __restrict__ WoT) {
  __shared__ unsigned short tile[64][72];
  const int k0 = blockIdx.x * 64;
  const int n0 = blockIdx.y * 64;
  const int t = threadIdx.x;
#pragma unroll
  for (int p = 0; p < 16; ++p) {
    int idx = p * 256 + t;
    int kk = idx >> 6, nn = idx & 63;
    tile[kk][nn] = f2bf(Wo[(size_t)(k0 + kk) * 1024 + n0 + nn]);
  }
  __syncthreads();
#pragma unroll
  for (int p = 0; p < 16; ++p) {
    int idx = p * 256 + t;
    int nn = idx >> 6, kk = idx & 63;
    WoT[(size_t)(n0 + nn) * 1024 + k0 + (kk ^ ((nn & 7) << 3))] = tile[kk][nn];
  }
}

// ---------------- GEMM: C = A[M,K] * BT[N,K]^T + bias ----------------
// m97 structure: 128x128 tile, BK=64, 4 waves (2x2), 4x4 16x16x32 frags/wave,
// global_load_lds width-16 staging, K-swizzled operands, LDS-bounce epilogue.
// MODE 0: QKV -> q [bh][t][d] PRE-SCALED by 0.125*log2(e) (attn works in exp2 domain),
//         k [bh][t][d^swz(t)],
//         vT [bh][t/64][d][ rot(t%64) ^ swz(d) ]  where rot places t-value at
//         slot q: q[5]=t[5], q[4:3]=t[3:2], q[2]=t[4], q[1:0]=t[1:0]
//         (matches attn's in-register P fragment permutation — see attn_fwd).
// MODE 1: f32 out + bias.

template <int MODE>
__global__ __launch_bounds__(256) void gemm_bt(
    const unsigned short* __restrict__ A, const unsigned short* __restrict__ BTm,
    const float* __restrict__ bias0, const float* __restrict__ bias1,
    const float* __restrict__ bias2,
    unsigned short* __restrict__ qo, unsigned short* __restrict__ ko,
    unsigned short* __restrict__ vto, float* __restrict__ outf,
    int K, int N) {
  __shared__ __align__(16) char lds[(MODE == 1) ? 36864 : 32768];
  unsigned short* As = (unsigned short*)lds;
  unsigned short* Bs = (unsigned short*)(lds + 16384);

  const int tid = threadIdx.x, lane = tid & 63, wv = tid >> 6;
  const int wr = wv >> 1, wc = wv & 1;
  const int g = lane >> 4, r = lane & 15;
  const int m0 = blockIdx.x * 128, n0 = blockIdx.y * 128;
  const int xr = (r & 7) << 4;

  f32x4 acc[4][4] = {};

  const int arow = tid >> 3;            // 0..31
  const int acol = (tid & 7) * 8;       // 0..56
  const unsigned short* Ab = A + (size_t)(m0 + arow) * K + acol;
  const unsigned short* Bb = BTm + (size_t)(n0 + arow) * K + acol;
  char* AsB = (char*)As + wv * 1024;
  char* BsB = (char*)Bs + wv * 1024;

  for (int k0 = 0; k0 < K; k0 += 64) {
#pragma unroll
    for (int i = 0; i < 4; ++i) {
      gld_lds16(Ab + (size_t)i * 32 * K + k0, AsB + i * 4096);
      gld_lds16(Bb + (size_t)i * 32 * K + k0, BsB + i * 4096);
    }
    __syncthreads();
    const char* Ar = (const char*)As;
    const char* Br = (const char*)Bs;
#pragma unroll
    for (int kk = 0; kk < 2; ++kk) {
      bf16x8 af[4], bfv[4];
#pragma unroll
      for (int f = 0; f < 4; ++f) {
        af[f]  = *(const bf16x8*)(Ar + (wr * 64 + f * 16 + r) * 128 + ((kk * 64 + g * 16) ^ xr));
        bfv[f] = *(const bf16x8*)(Br + (wc * 64 + f * 16 + r) * 128 + ((kk * 64 + g * 16) ^ xr));
      }
#pragma unroll
      for (int fm = 0; fm < 4; ++fm)
#pragma unroll
        for (int fn = 0; fn < 4; ++fn)
          acc[fm][fn] = __builtin_amdgcn_mfma_f32_16x16x32_bf16(af[fm], bfv[fn], acc[fm][fn], 0, 0, 0);
    }
    __syncthreads();
  }

  // ---------------- LDS-bounce epilogue: coalesced stores ----------------
  if (MODE == 0) {
    const int which = n0 >> 10;  // 0=q 1=k 2=v (uniform per block)
    const float* bias = (which == 0) ? bias0 : (which == 1) ? bias1 : bias2;
    const float sc = (which == 0) ? 0.18033688011112042f : 1.0f;  // 0.125*log2(e)
    const int b = m0 >> 11;
    const int t0 = m0 & 2047;
    unsigned short* ep = (unsigned short*)lds;

#pragma unroll
    for (int h = 0; h < 2; ++h) {   // 64-col half == one head's d-range
      const int head = ((n0 & 1023) + h * 64) >> 6;
      const size_t bhb = (size_t)(b * NHEAD + head) * 131072;
      __syncthreads();
      if (wc == h) {
        if (which == 2) {
          // transposed tile: ep[d][t], pitch 136 elems (272B, 16B-aligned rows)
#pragma unroll
          for (int fn = 0; fn < 4; ++fn) {
            const int d = fn * 16 + r;
            const float bvl = bias[head * 64 + d];
#pragma unroll
            for (int fm = 0; fm < 4; ++fm)
#pragma unroll
              for (int j = 0; j < 4; ++j) {
                const int t = wr * 64 + fm * 16 + 4 * g + j;
                ep[d * 136 + t] = f2bf(acc[fm][fn][j] + bvl);
              }
          }
        } else {
          // tile: ep[t][d], pitch 72 elems (144B, 16B-aligned rows)
#pragma unroll
          for (int fn = 0; fn < 4; ++fn) {
            const int d = fn * 16 + r;
            const float bvl = bias[head * 64 + d];
#pragma unroll
            for (int fm = 0; fm < 4; ++fm)
#pragma unroll
              for (int j = 0; j < 4; ++j) {
                const int t = wr * 64 + fm * 16 + 4 * g + j;
                ep[t * 72 + d] = f2bf((acc[fm][fn][j] + bvl) * sc);
              }
          }
        }
      }
      __syncthreads();
      if (which == 2) {
        // permuted+swizzled V^T store: 16B store = slots q_base..+7;
        // slot q holds t = (q&32) + (q&4)*4 + ((q>>3)&3)*4 + (q&3)
#pragma unroll
        for (int p = 0; p < 4; ++p) {
          const int d = p * 16 + (tid >> 4);
          const int u = tid & 15;
          const int c = u >> 3;          // which 64-t chunk of the 128-t tile
          const int w = u & 7;           // q_base/8: bits [2]=kk, [1:0]=g
          const int kk = w >> 2, gg = w & 3;
          const int base_t = c * 64 + kk * 32 + 4 * gg;
          union { bf16x4 h4[2]; bf16x8 v8; } cc2;
          cc2.h4[0] = *(const bf16x4*)(ep + d * 136 + base_t);        // h=0: j=0..3
          cc2.h4[1] = *(const bf16x4*)(ep + d * 136 + base_t + 16);   // h=1: j=0..3
          const int q_base = w * 8;
          *(bf16x8*)(vto + bhb + (size_t)((t0 >> 6) + c) * 4096 + (size_t)d * 64 +
                     (q_base ^ ((d & 7) << 3))) = cc2.v8;
        }
      } else {
        unsigned short* qk = (which == 1) ? ko : qo;
        // store 128 t-rows x 64 d: 8 lanes/row, 4 passes
#pragma unroll
        for (int p = 0; p < 4; ++p) {
          const int row = p * 32 + (tid >> 3);
          const int seg = tid & 7;
          const bf16x8 v8 = *(const bf16x8*)(ep + row * 72 + seg * 8);
          const int tt = t0 + row;
          int dbase = seg * 8;
          if (which == 1) dbase ^= (tt & 7) << 3;
          *(bf16x8*)(qk + bhb + (size_t)tt * 64 + dbase) = v8;
        }
      }
    }
  } else {
    float* epf = (float*)lds;   // [128][68 f32] pitch 272B
#pragma unroll
    for (int h = 0; h < 2; ++h) {
      __syncthreads();
      if (wc == h) {
#pragma unroll
        for (int fn = 0; fn < 4; ++fn) {
          const int n = n0 + h * 64 + fn * 16 + r;
          const float bvl = bias0[n];
#pragma unroll
          for (int fm = 0; fm < 4; ++fm)
#pragma unroll
            for (int j = 0; j < 4; ++j)
              epf[(wr * 64 + fm * 16 + 4 * g + j) * 68 + fn * 16 + r] = acc[fm][fn][j] + bvl;
        }
      }
      __syncthreads();
#pragma unroll
      for (int p = 0; p < 8; ++p) {
        const int row = p * 16 + (tid >> 4);
        const int seg = tid & 15;
        const f32x4 v4 = *(const f32x4*)(epf + row * 68 + seg * 4);
        *(f32x4*)(outf + (size_t)(m0 + row) * N + n0 + h * 64 + seg * 4) = v4;
      }
    }
  }
}

// ---------------- flash attention (causal) ----------------
// Swapped QK^T (lane owns q=r); P in registers (permuted PV contraction axis,
// matching V's global layout). Softmax common path has ZERO cross-lane ops:
//  - q pre-scaled by 0.125*log2e in GEMM -> S already in log2 domain, exp2 direct
//  - defer-max check via per-lane partial max + __all (row shuffles only in the
//    rare rescale branch)
//  - l kept as per-lane partial sums, reduced across g once at the end.

__global__ __launch_bounds__(256) void attn_fwd(const unsigned short* __restrict__ Qm,
                                                const unsigned short* __restrict__ Km,
                                                const unsigned short* __restrict__ Vtm,
                                                unsigned short* __restrict__ Om) {
  __shared__ __align__(16) unsigned short Ks[2][4096];
  __shared__ __align__(16) unsigned short Vs[2][4096];

  const int tid = threadIdx.x, lane = tid & 63, wv = tid >> 6;
  const int g = lane >> 4, r = lane & 15;
  const int bh = blockIdx.x & 63;
  const int qp = 15 - (blockIdx.x >> 6);      // heavy blocks dispatch first

  const unsigned short* Qp = Qm + (size_t)bh * 131072;
  const unsigned short* Kp = Km + (size_t)bh * 131072;
  const unsigned short* Vp = Vtm + (size_t)bh * 131072;

  const int qb[2] = {qp * 128 + wv * 16, qp * 128 + 64 + wv * 16};

  bf16x8 qf[2][2];
#pragma unroll
  for (int mi = 0; mi < 2; ++mi)
#pragma unroll
    for (int h2 = 0; h2 < 2; ++h2)
      qf[mi][h2] = *(const bf16x8*)(Qp + (size_t)(qb[mi] + r) * 64 + h2 * 32 + g * 8);

  f32x4 oacc[2][4] = {};
  float m_[2] = {-__builtin_inff(), -__builtin_inff()};
  float l_[2] = {0.f, 0.f};    // per-lane partial sums (this lane's g-slice)

#define ASTAGE(buf, c) do {                                                      \
    const unsigned short* kg_ = Kp + (size_t)(c) * 4096;                         \
    const unsigned short* vg_ = Vp + (size_t)(c) * 4096;                         \
    const int o0_ = wv * 1024;                                                   \
    gld_lds16(kg_ + (o0_ >> 1) + lane * 8, (char*)Ks[buf] + o0_);                \
    gld_lds16(vg_ + (o0_ >> 1) + lane * 8, (char*)Vs[buf] + o0_);                \
    gld_lds16(kg_ + ((o0_ + 4096) >> 1) + lane * 8, (char*)Ks[buf] + o0_ + 4096);\
    gld_lds16(vg_ + ((o0_ + 4096) >> 1) + lane * 8, (char*)Vs[buf] + o0_ + 4096);\
  } while (0)

  const int nt = qp * 2 + 2;
  ASTAGE(0, 0);
  __syncthreads();

  for (int t = 0; t < nt; ++t) {
    const int cur = t & 1;
    if (t + 1 < nt) ASTAGE(cur ^ 1, t + 1);

    const char* KsT = (const char*)Ks[cur];
    const char* VsT = (const char*)Vs[cur];
    const int sw = (r & 7) << 4;
    bf16x8 kf[4][2], vf[4][2];
#pragma unroll
    for (int tt = 0; tt < 4; ++tt) {
      const int rowb = (tt * 16 + r) * 128;
#pragma unroll
      for (int kk = 0; kk < 2; ++kk) {
        const int cb = (kk * 64 + g * 16) ^ sw;
        kf[tt][kk] = *(const bf16x8*)(KsT + rowb + cb);
        vf[tt][kk] = *(const bf16x8*)(VsT + rowb + cb);
      }
    }

#pragma unroll
    for (int mi = 0; mi < 2; ++mi) {
      const int qbm = qb[mi];
      if (t * 64 > qbm + 15) continue;   // frag fully masked (wave-uniform)

      // S^T[kv][q] = K Q^T (log2 domain): lane holds q = r, kv = 16tt + 4g + j
      f32x4 sT[4];
      __builtin_amdgcn_s_setprio(1);
#pragma unroll
      for (int tt = 0; tt < 4; ++tt) {
        f32x4 a = {0.f, 0.f, 0.f, 0.f};
        a = __builtin_amdgcn_mfma_f32_16x16x32_bf16(kf[tt][0], qf[mi][0], a, 0, 0, 0);
        a = __builtin_amdgcn_mfma_f32_16x16x32_bf16(kf[tt][1], qf[mi][1], a, 0, 0, 0);
        sT[tt] = a;
      }
      __builtin_amdgcn_s_setprio(0);

      const int qg = qbm + r;
      if (t * 64 + 63 > qbm) {           // diagonal tile: per-element causal mask
#pragma unroll
        for (int tt = 0; tt < 4; ++tt)
#pragma unroll
          for (int j = 0; j < 4; ++j) {
            const int kv = t * 64 + tt * 16 + 4 * g + j;
            sT[tt][j] = (kv <= qg) ? sT[tt][j] : -__builtin_inff();
          }
      }

      // per-lane partial max (tree; no cross-lane)
      float tm[4];
#pragma unroll
      for (int tt = 0; tt < 4; ++tt)
        tm[tt] = fmaxf(fmaxf(sT[tt][0], sT[tt][1]), fmaxf(sT[tt][2], sT[tt][3]));
      const float mx = fmaxf(fmaxf(tm[0], tm[1]), fmaxf(tm[2], tm[3]));

      float mcur = m_[mi];
      const bool norescale = __all(mx <= mcur + 4.0f);   // defer-max, per-lane check
      if (!norescale) {
        // rare: full row max + rescale (shuffles only here)
        float rmx = mx;
        rmx = fmaxf(rmx, __shfl_xor(rmx, 16));
        rmx = fmaxf(rmx, __shfl_xor(rmx, 32));
        const float mnew = fmaxf(mcur, rmx);
        const float rs = fexp2(mcur - mnew);
        m_[mi] = mnew;
        mcur = mnew;
        l_[mi] *= rs;                      // per-lane partial, row-uniform rs
        float rsb[4];
#pragma unroll
        for (int j = 0; j < 4; ++j) rsb[j] = __shfl(rs, 4 * g + j);
#pragma unroll
        for (int df = 0; df < 4; ++df)
#pragma unroll
          for (int j = 0; j < 4; ++j) oacc[mi][df][j] *= rsb[j];
      }

      // P = exp2(S - m); per-lane partial sum
      float ts = 0.f;
#pragma unroll
      for (int tt = 0; tt < 4; ++tt)
#pragma unroll
        for (int j = 0; j < 4; ++j) {
          const float p = fexp2(sT[tt][j] - mcur);
          sT[tt][j] = p;
          ts += p;
        }
      l_[mi] += ts;

      // P -> bf16 A-fragments, fully in-register (permuted contraction axis)
      union { uint32_t w[8]; bf16x8 v[2]; } pu;
#pragma unroll
      for (int tt = 0; tt < 4; ++tt) {
        asm("v_cvt_pk_bf16_f32 %0, %1, %2" : "=v"(pu.w[2 * tt])
            : "v"(sT[tt][0]), "v"(sT[tt][1]));
        asm("v_cvt_pk_bf16_f32 %0, %1, %2" : "=v"(pu.w[2 * tt + 1])
            : "v"(sT[tt][2]), "v"(sT[tt][3]));
      }

      __builtin_amdgcn_s_setprio(1);
#pragma unroll
      for (int kk = 0; kk < 2; ++kk)
#pragma unroll
        for (int df = 0; df < 4; ++df)
          oacc[mi][df] = __builtin_amdgcn_mfma_f32_16x16x32_bf16(pu.v[kk], vf[df][kk], oacc[mi][df], 0, 0, 0);
      __builtin_amdgcn_s_setprio(0);
    }
    __syncthreads();
  }
#undef ASTAGE

  // write concat layout [B,T,1024], K-swizzled for O-proj A-operand
  const int b = bh >> 4, h = bh & 15;
#pragma unroll
  for (int mi = 0; mi < 2; ++mi) {
    // reduce per-lane partial l across the 4 g-lanes of each row (once)
    float lt = l_[mi];
    lt += __shfl_xor(lt, 16);
    lt += __shfl_xor(lt, 32);
    float inv[4];
#pragma unroll
    for (int j = 0; j < 4; ++j) {
      const float lb = __shfl(lt, 4 * g + j);
      inv[j] = __builtin_amdgcn_rcpf(lb);
    }
#pragma unroll
    for (int df = 0; df < 4; ++df)
#pragma unroll
      for (int j = 0; j < 4; ++j) {
        const int trow = qb[mi] + 4 * g + j;
        const float ov = oacc[mi][df][j] * inv[j];
        const int col = (df * 16 + r) ^ ((trow & 7) << 3);
        Om[((size_t)(b * TSEQ + trow)) * 1024 + h * 64 + col] = f2bf(ov);
      }
  }
}

// ---------------- launch ----------------

extern "C" void kernel_launch(void* const* d_in, const int* in_sizes, int n_in,
                              void* d_out, int out_size, void* d_ws, size_t ws_size,
                              hipStream_t stream) {
  const float* x  = (const float*)d_in[0];
  const float* Wq = (const float*)d_in[1];
  const float* bq = (const float*)d_in[2];
  const float* Wk = (const float*)d_in[3];
  const float* bk = (const float*)d_in[4];
  const float* Wv = (const float*)d_in[5];
  const float* bv = (const float*)d_in[6];
  const float* Wo = (const float*)d_in[7];
  const float* bo = (const float*)d_in[8];
  float* out = (float*)d_out;

  unsigned short* xb  = (unsigned short*)d_ws;               // 8192*1024
  unsigned short* btq = xb + (size_t)8192 * 1024;            // 3072*1024
  unsigned short* wot = btq + (size_t)3072 * 1024;           // 1024*1024
  unsigned short* qb  = wot + (size_t)1024 * 1024;           // 64*2048*64
  unsigned short* kb  = qb + (size_t)64 * 2048 * 64;
  unsigned short* vtb = kb + (size_t)64 * 2048 * 64;

  cast_x_kernel<<<8192, 256, 0, stream>>>((const float4*)x, xb);
  repack_wqkv<<<dim3(16, 16, 3), 256, 0, stream>>>(Wq, Wk, Wv, btq);
  repack_wo<<<dim3(16, 16), 256, 0, stream>>>(Wo, wot);

  // QKV: [8192,1024] x [1024,3072] -> q/k/vT (attn layouts; q pre-scaled)
  gemm_bt<0><<<dim3(64, 24), 256, 0, stream>>>(xb, btq, bq, bk, bv, qb, kb, vtb,
                                               nullptr, 1024, 3072);
  // attention: 16 qp (heavy first) x 64 bh
  attn_fwd<<<1024, 256, 0, stream>>>(qb, kb, vtb, xb);
  // O-proj: [8192,1024] x [1024,1024] -> f32 out
  gemm_bt<1><<<dim3(64, 8), 256, 0, stream>>>(xb, wot, bo, nullptr, nullptr,
                                              nullptr, nullptr, nullptr, out,
                                              1024, 1024);
}

// Round 7
// 177.625 us; speedup vs baseline: 3.3624x; 1.0237x over previous
//
#include <hip/hip_runtime.h>
#include <stdint.h>

#define TSEQ 2048
#define NHEAD 16

typedef __attribute__((ext_vector_type(8))) short bf16x8;
typedef __attribute__((ext_vector_type(4))) short bf16x4;
typedef __attribute__((ext_vector_type(4))) float f32x4;

__device__ __forceinline__ unsigned short f2bf(float f) {
  union { float f; uint32_t u; } c;
  c.f = f;
  uint32_t u = c.u;
  u += 0x7fffu + ((u >> 16) & 1u);   // round-nearest-even
  return (unsigned short)(u >> 16);
}

__device__ __forceinline__ float fexp2(float x) {
#if __has_builtin(__builtin_amdgcn_exp2f)
  return __builtin_amdgcn_exp2f(x);
#else
  return __builtin_exp2f(x);
#endif
}

using as3_void  = __attribute__((address_space(3))) void;
using as1_cvoid = const __attribute__((address_space(1))) void;

__device__ __forceinline__ void gld_lds16(const void* g, void* l) {
  // async global->LDS, 16B/lane; LDS dest = wave-uniform base + lane*16
  __builtin_amdgcn_global_load_lds((as1_cvoid*)g, (as3_void*)l, 16, 0, 0);
}

// ---------------- prep kernels (produce K-swizzled global layouts) ----------------
// GEMM operand layout: X'[row][k] = X[row][k ^ ((row&7)<<3)] within each 64-elem k-block.
// gld_lds fills LDS linearly; ds_read applies the same XOR -> bank-balanced (0 conflicts, R3).

__global__ void cast_x_kernel(const float4* __restrict__ x, unsigned short* __restrict__ xb) {
  int i = blockIdx.x * 256 + threadIdx.x;   // group of 4 elems
  float4 v = x[i];
  int e = i * 4;
  int m = e >> 10, k = e & 1023;
  int ks = k ^ ((m & 7) << 3);
  ushort4 o;
  o.x = f2bf(v.x); o.y = f2bf(v.y); o.z = f2bf(v.z); o.w = f2bf(v.w);
  *(ushort4*)(xb + (size_t)m * 1024 + ks) = o;
}

// Wq/Wk/Wv [H,C,HD] f32 -> BT[(which*1024 + h*64 + d)][c ^ swz(d)] bf16
__global__ void repack_wqkv(const float* __restrict__ Wq, const float* __restrict__ Wk,
                            const float* __restrict__ Wv, unsigned short* __restrict__ BT) {
  __shared__ unsigned short tile[64][72];
  const float* W = (blockIdx.z == 0) ? Wq : (blockIdx.z == 1) ? Wk : Wv;
  const int h = blockIdx.y;
  const int c0 = blockIdx.x * 64;
  const int t = threadIdx.x;
  const float* src = W + ((size_t)h * 1024 + c0) * 64;
#pragma unroll
  for (int p = 0; p < 16; ++p) {
    int idx = p * 256 + t;
    int cc = idx >> 6, d = idx & 63;
    tile[cc][d] = f2bf(src[(size_t)cc * 64 + d]);
  }
  __syncthreads();
  unsigned short* dst = BT + ((size_t)blockIdx.z * 1024 + (size_t)h * 64) * 1024 + c0;
#pragma unroll
  for (int p = 0; p < 16; ++p) {
    int idx = p * 256 + t;
    int d = idx >> 6, cc = idx & 63;
    dst[(size_t)d * 1024 + (cc ^ ((d & 7) << 3))] = tile[cc][d];
  }
}

// Wo [C,C] f32 -> WoT[n][k ^ swz(n)] bf16 (transpose + swizzle)
__global__ void repack_wo(const float* __restrict__ Wo, unsigned short* __restrict__ WoT) {
  __shared__ unsigned short tile[64][72];
  const int k0 = blockIdx.x * 64;
  const int n0 = blockIdx.y * 64;
  const int t = threadIdx.x;
#pragma unroll
  for (int p = 0; p < 16; ++p) {
    int idx = p * 256 + t;
    int kk = idx >> 6, nn = idx & 63;
    tile[kk][nn] = f2bf(Wo[(size_t)(k0 + kk) * 1024 + n0 + nn]);
  }
  __syncthreads();
#pragma unroll
  for (int p = 0; p < 16; ++p) {
    int idx = p * 256 + t;
    int nn = idx >> 6, kk = idx & 63;
    WoT[(size_t)(n0 + nn) * 1024 + k0 + (kk ^ ((nn & 7) << 3))] = tile[kk][nn];
  }
}

// ---------------- GEMM: C = A[M,K] * BT[N,K]^T + bias ----------------
// 128x128 tile, BK=64, 4 waves (2x2), 4x4 16x16x32 frags/wave, K-swizzled operands.
// DOUBLE-BUFFERED staging with stage-early / drain-late (attn-proven pattern):
// iter t issues global_load_lds for tile t+1 into buf nxt BEFORE computing buf cur;
// the end-of-iter __syncthreads (compiler vmcnt(0)) drains them AFTER compute
// covered the latency. Only the prologue stage is latency-exposed.
// Epilogue: LDS-bounce re-layout -> fully coalesced b128 global stores.
// MODE 0: QKV -> q [bh][t][d] PRE-SCALED by 0.125*log2(e),
//         k [bh][t][d^swz(t)],
//         vT [bh][t/64][d][ rot(t%64) ^ swz(d) ] (rot matches attn's in-reg P perm)
// MODE 1: f32 out + bias.

template <int MODE>
__global__ __launch_bounds__(256) void gemm_bt(
    const unsigned short* __restrict__ A, const unsigned short* __restrict__ BTm,
    const float* __restrict__ bias0, const float* __restrict__ bias1,
    const float* __restrict__ bias2,
    unsigned short* __restrict__ qo, unsigned short* __restrict__ ko,
    unsigned short* __restrict__ vto, float* __restrict__ outf,
    int K, int N) {
  __shared__ __align__(16) char lds[65536];   // 2 buf x (A 16K + B 16K)

  const int tid = threadIdx.x, lane = tid & 63, wv = tid >> 6;
  const int wr = wv >> 1, wc = wv & 1;
  const int g = lane >> 4, r = lane & 15;
  const int m0 = blockIdx.x * 128, n0 = blockIdx.y * 128;
  const int xr = (r & 7) << 4;

  f32x4 acc[4][4] = {};

  const int arow = tid >> 3;            // 0..31
  const int acol = (tid & 7) * 8;       // 0..56
  const unsigned short* Ab = A + (size_t)(m0 + arow) * K + acol;
  const unsigned short* Bb = BTm + (size_t)(n0 + arow) * K + acol;

#define GSTAGE(b, kel) do {                                                 \
    char* ab_ = lds + (b) * 32768 + wv * 1024;                              \
    _Pragma("unroll") for (int i = 0; i < 4; ++i) {                         \
      gld_lds16(Ab + (size_t)i * 32 * K + (kel), ab_ + i * 4096);           \
      gld_lds16(Bb + (size_t)i * 32 * K + (kel), ab_ + 16384 + i * 4096);   \
    } } while (0)

  const int NT = K >> 6;
  GSTAGE(0, 0);
  __syncthreads();                       // tile 0 exposed (once)

  for (int t = 0; t < NT; ++t) {
    const int cur = t & 1;
    if (t + 1 < NT) GSTAGE(cur ^ 1, (t + 1) << 6);   // issue BEFORE compute
    const char* Ar = lds + cur * 32768;
    const char* Br = Ar + 16384;
#pragma unroll
    for (int kk = 0; kk < 2; ++kk) {
      bf16x8 af[4], bfv[4];
#pragma unroll
      for (int f = 0; f < 4; ++f) {
        af[f]  = *(const bf16x8*)(Ar + (wr * 64 + f * 16 + r) * 128 + ((kk * 64 + g * 16) ^ xr));
        bfv[f] = *(const bf16x8*)(Br + (wc * 64 + f * 16 + r) * 128 + ((kk * 64 + g * 16) ^ xr));
      }
#pragma unroll
      for (int fm = 0; fm < 4; ++fm)
#pragma unroll
        for (int fn = 0; fn < 4; ++fn)
          acc[fm][fn] = __builtin_amdgcn_mfma_f32_16x16x32_bf16(af[fm], bfv[fn], acc[fm][fn], 0, 0, 0);
    }
    __syncthreads();                     // drains tile t+1 loads (latency hidden)
  }
#undef GSTAGE

  // ---------------- LDS-bounce epilogue: coalesced stores ----------------
  if (MODE == 0) {
    const int which = n0 >> 10;  // 0=q 1=k 2=v (uniform per block)
    const float* bias = (which == 0) ? bias0 : (which == 1) ? bias1 : bias2;
    const float sc = (which == 0) ? 0.18033688011112042f : 1.0f;  // 0.125*log2(e)
    const int b = m0 >> 11;
    const int t0 = m0 & 2047;
    unsigned short* ep = (unsigned short*)lds;

#pragma unroll
    for (int h = 0; h < 2; ++h) {   // 64-col half == one head's d-range
      const int head = ((n0 & 1023) + h * 64) >> 6;
      const size_t bhb = (size_t)(b * NHEAD + head) * 131072;
      __syncthreads();
      if (wc == h) {
        if (which == 2) {
          // transposed tile: ep[d][t], pitch 136 elems (272B, 16B-aligned rows)
#pragma unroll
          for (int fn = 0; fn < 4; ++fn) {
            const int d = fn * 16 + r;
            const float bvl = bias[head * 64 + d];
#pragma unroll
            for (int fm = 0; fm < 4; ++fm)
#pragma unroll
              for (int j = 0; j < 4; ++j) {
                const int t = wr * 64 + fm * 16 + 4 * g + j;
                ep[d * 136 + t] = f2bf(acc[fm][fn][j] + bvl);
              }
          }
        } else {
          // tile: ep[t][d], pitch 72 elems (144B, 16B-aligned rows)
#pragma unroll
          for (int fn = 0; fn < 4; ++fn) {
            const int d = fn * 16 + r;
            const float bvl = bias[head * 64 + d];
#pragma unroll
            for (int fm = 0; fm < 4; ++fm)
#pragma unroll
              for (int j = 0; j < 4; ++j) {
                const int t = wr * 64 + fm * 16 + 4 * g + j;
                ep[t * 72 + d] = f2bf((acc[fm][fn][j] + bvl) * sc);
              }
          }
        }
      }
      __syncthreads();
      if (which == 2) {
        // permuted+swizzled V^T store: 16B store = slots q_base..+7;
        // slot q holds t = (q&32) + (q&4)*4 + ((q>>3)&3)*4 + (q&3)
#pragma unroll
        for (int p = 0; p < 4; ++p) {
          const int d = p * 16 + (tid >> 4);
          const int u = tid & 15;
          const int c = u >> 3;          // which 64-t chunk of the 128-t tile
          const int w = u & 7;           // q_base/8: bits [2]=kk, [1:0]=g
          const int kk = w >> 2, gg = w & 3;
          const int base_t = c * 64 + kk * 32 + 4 * gg;
          union { bf16x4 h4[2]; bf16x8 v8; } cc2;
          cc2.h4[0] = *(const bf16x4*)(ep + d * 136 + base_t);        // h=0: j=0..3
          cc2.h4[1] = *(const bf16x4*)(ep + d * 136 + base_t + 16);   // h=1: j=0..3
          const int q_base = w * 8;
          *(bf16x8*)(vto + bhb + (size_t)((t0 >> 6) + c) * 4096 + (size_t)d * 64 +
                     (q_base ^ ((d & 7) << 3))) = cc2.v8;
        }
      } else {
        unsigned short* qk = (which == 1) ? ko : qo;
        // store 128 t-rows x 64 d: 8 lanes/row, 4 passes
#pragma unroll
        for (int p = 0; p < 4; ++p) {
          const int row = p * 32 + (tid >> 3);
          const int seg = tid & 7;
          const bf16x8 v8 = *(const bf16x8*)(ep + row * 72 + seg * 8);
          const int tt = t0 + row;
          int dbase = seg * 8;
          if (which == 1) dbase ^= (tt & 7) << 3;
          *(bf16x8*)(qk + bhb + (size_t)tt * 64 + dbase) = v8;
        }
      }
    }
  } else {
    float* epf = (float*)lds;   // [128][68 f32] pitch 272B
#pragma unroll
    for (int h = 0; h < 2; ++h) {
      __syncthreads();
      if (wc == h) {
#pragma unroll
        for (int fn = 0; fn < 4; ++fn) {
          const int n = n0 + h * 64 + fn * 16 + r;
          const float bvl = bias0[n];
#pragma unroll
          for (int fm = 0; fm < 4; ++fm)
#pragma unroll
            for (int j = 0; j < 4; ++j)
              epf[(wr * 64 + fm * 16 + 4 * g + j) * 68 + fn * 16 + r] = acc[fm][fn][j] + bvl;
        }
      }
      __syncthreads();
#pragma unroll
      for (int p = 0; p < 8; ++p) {
        const int row = p * 16 + (tid >> 4);
        const int seg = tid & 15;
        const f32x4 v4 = *(const f32x4*)(epf + row * 68 + seg * 4);
        *(f32x4*)(outf + (size_t)(m0 + row) * N + n0 + h * 64 + seg * 4) = v4;
      }
    }
  }
}

// ---------------- flash attention (causal) ----------------
// Swapped QK^T (lane owns q=r); P in registers (permuted PV contraction axis,
// matching V's global layout). Softmax common path has ZERO cross-lane ops:
//  - q pre-scaled by 0.125*log2e in GEMM -> S already in log2 domain, exp2 direct
//  - defer-max check via per-lane partial max + __all (row shuffles only in the
//    rare rescale branch)
//  - l kept as per-lane partial sums, reduced across g once at the end.

__global__ __launch_bounds__(256) void attn_fwd(const unsigned short* __restrict__ Qm,
                                                const unsigned short* __restrict__ Km,
                                                const unsigned short* __restrict__ Vtm,
                                                unsigned short* __restrict__ Om) {
  __shared__ __align__(16) unsigned short Ks[2][4096];
  __shared__ __align__(16) unsigned short Vs[2][4096];

  const int tid = threadIdx.x, lane = tid & 63, wv = tid >> 6;
  const int g = lane >> 4, r = lane & 15;
  const int bh = blockIdx.x & 63;
  const int qp = 15 - (blockIdx.x >> 6);      // heavy blocks dispatch first

  const unsigned short* Qp = Qm + (size_t)bh * 131072;
  const unsigned short* Kp = Km + (size_t)bh * 131072;
  const unsigned short* Vp = Vtm + (size_t)bh * 131072;

  const int qb[2] = {qp * 128 + wv * 16, qp * 128 + 64 + wv * 16};

  bf16x8 qf[2][2];
#pragma unroll
  for (int mi = 0; mi < 2; ++mi)
#pragma unroll
    for (int h2 = 0; h2 < 2; ++h2)
      qf[mi][h2] = *(const bf16x8*)(Qp + (size_t)(qb[mi] + r) * 64 + h2 * 32 + g * 8);

  f32x4 oacc[2][4] = {};
  float m_[2] = {-__builtin_inff(), -__builtin_inff()};
  float l_[2] = {0.f, 0.f};    // per-lane partial sums (this lane's g-slice)

#define ASTAGE(buf, c) do {                                                      \
    const unsigned short* kg_ = Kp + (size_t)(c) * 4096;                         \
    const unsigned short* vg_ = Vp + (size_t)(c) * 4096;                         \
    const int o0_ = wv * 1024;                                                   \
    gld_lds16(kg_ + (o0_ >> 1) + lane * 8, (char*)Ks[buf] + o0_);                \
    gld_lds16(vg_ + (o0_ >> 1) + lane * 8, (char*)Vs[buf] + o0_);                \
    gld_lds16(kg_ + ((o0_ + 4096) >> 1) + lane * 8, (char*)Ks[buf] + o0_ + 4096);\
    gld_lds16(vg_ + ((o0_ + 4096) >> 1) + lane * 8, (char*)Vs[buf] + o0_ + 4096);\
  } while (0)

  const int nt = qp * 2 + 2;
  ASTAGE(0, 0);
  __syncthreads();

  for (int t = 0; t < nt; ++t) {
    const int cur = t & 1;
    if (t + 1 < nt) ASTAGE(cur ^ 1, t + 1);

    const char* KsT = (const char*)Ks[cur];
    const char* VsT = (const char*)Vs[cur];
    const int sw = (r & 7) << 4;
    bf16x8 kf[4][2], vf[4][2];
#pragma unroll
    for (int tt = 0; tt < 4; ++tt) {
      const int rowb = (tt * 16 + r) * 128;
#pragma unroll
      for (int kk = 0; kk < 2; ++kk) {
        const int cb = (kk * 64 + g * 16) ^ sw;
        kf[tt][kk] = *(const bf16x8*)(KsT + rowb + cb);
        vf[tt][kk] = *(const bf16x8*)(VsT + rowb + cb);
      }
    }

#pragma unroll
    for (int mi = 0; mi < 2; ++mi) {
      const int qbm = qb[mi];
      if (t * 64 > qbm + 15) continue;   // frag fully masked (wave-uniform)

      // S^T[kv][q] = K Q^T (log2 domain): lane holds q = r, kv = 16tt + 4g + j
      f32x4 sT[4];
      __builtin_amdgcn_s_setprio(1);
#pragma unroll
      for (int tt = 0; tt < 4; ++tt) {
        f32x4 a = {0.f, 0.f, 0.f, 0.f};
        a = __builtin_amdgcn_mfma_f32_16x16x32_bf16(kf[tt][0], qf[mi][0], a, 0, 0, 0);
        a = __builtin_amdgcn_mfma_f32_16x16x32_bf16(kf[tt][1], qf[mi][1], a, 0, 0, 0);
        sT[tt] = a;
      }
      __builtin_amdgcn_s_setprio(0);

      const int qg = qbm + r;
      if (t * 64 + 63 > qbm) {           // diagonal tile: per-element causal mask
#pragma unroll
        for (int tt = 0; tt < 4; ++tt)
#pragma unroll
          for (int j = 0; j < 4; ++j) {
            const int kv = t * 64 + tt * 16 + 4 * g + j;
            sT[tt][j] = (kv <= qg) ? sT[tt][j] : -__builtin_inff();
          }
      }

      // per-lane partial max (tree; no cross-lane)
      float tm[4];
#pragma unroll
      for (int tt = 0; tt < 4; ++tt)
        tm[tt] = fmaxf(fmaxf(sT[tt][0], sT[tt][1]), fmaxf(sT[tt][2], sT[tt][3]));
      const float mx = fmaxf(fmaxf(tm[0], tm[1]), fmaxf(tm[2], tm[3]));

      float mcur = m_[mi];
      const bool norescale = __all(mx <= mcur + 4.0f);   // defer-max, per-lane check
      if (!norescale) {
        // rare: full row max + rescale (shuffles only here)
        float rmx = mx;
        rmx = fmaxf(rmx, __shfl_xor(rmx, 16));
        rmx = fmaxf(rmx, __shfl_xor(rmx, 32));
        const float mnew = fmaxf(mcur, rmx);
        const float rs = fexp2(mcur - mnew);
        m_[mi] = mnew;
        mcur = mnew;
        l_[mi] *= rs;                      // per-lane partial, row-uniform rs
        float rsb[4];
#pragma unroll
        for (int j = 0; j < 4; ++j) rsb[j] = __shfl(rs, 4 * g + j);
#pragma unroll
        for (int df = 0; df < 4; ++df)
#pragma unroll
          for (int j = 0; j < 4; ++j) oacc[mi][df][j] *= rsb[j];
      }

      // P = exp2(S - m); per-lane partial sum
      float ts = 0.f;
#pragma unroll
      for (int tt = 0; tt < 4; ++tt)
#pragma unroll
        for (int j = 0; j < 4; ++j) {
          const float p = fexp2(sT[tt][j] - mcur);
          sT[tt][j] = p;
          ts += p;
        }
      l_[mi] += ts;

      // P -> bf16 A-fragments, fully in-register (permuted contraction axis)
      union { uint32_t w[8]; bf16x8 v[2]; } pu;
#pragma unroll
      for (int tt = 0; tt < 4; ++tt) {
        asm("v_cvt_pk_bf16_f32 %0, %1, %2" : "=v"(pu.w[2 * tt])
            : "v"(sT[tt][0]), "v"(sT[tt][1]));
        asm("v_cvt_pk_bf16_f32 %0, %1, %2" : "=v"(pu.w[2 * tt + 1])
            : "v"(sT[tt][2]), "v"(sT[tt][3]));
      }

      __builtin_amdgcn_s_setprio(1);
#pragma unroll
      for (int kk = 0; kk < 2; ++kk)
#pragma unroll
        for (int df = 0; df < 4; ++df)
          oacc[mi][df] = __builtin_amdgcn_mfma_f32_16x16x32_bf16(pu.v[kk], vf[df][kk], oacc[mi][df], 0, 0, 0);
      __builtin_amdgcn_s_setprio(0);
    }
    __syncthreads();
  }
#undef ASTAGE

  // write concat layout [B,T,1024], K-swizzled for O-proj A-operand
  const int b = bh >> 4, h = bh & 15;
#pragma unroll
  for (int mi = 0; mi < 2; ++mi) {
    // reduce per-lane partial l across the 4 g-lanes of each row (once)
    float lt = l_[mi];
    lt += __shfl_xor(lt, 16);
    lt += __shfl_xor(lt, 32);
    float inv[4];
#pragma unroll
    for (int j = 0; j < 4; ++j) {
      const float lb = __shfl(lt, 4 * g + j);
      inv[j] = __builtin_amdgcn_rcpf(lb);
    }
#pragma unroll
    for (int df = 0; df < 4; ++df)
#pragma unroll
      for (int j = 0; j < 4; ++j) {
        const int trow = qb[mi] + 4 * g + j;
        const float ov = oacc[mi][df][j] * inv[j];
        const int col = (df * 16 + r) ^ ((trow & 7) << 3);
        Om[((size_t)(b * TSEQ + trow)) * 1024 + h * 64 + col] = f2bf(ov);
      }
  }
}

// ---------------- launch ----------------

extern "C" void kernel_launch(void* const* d_in, const int* in_sizes, int n_in,
                              void* d_out, int out_size, void* d_ws, size_t ws_size,
                              hipStream_t stream) {
  const float* x  = (const float*)d_in[0];
  const float* Wq = (const float*)d_in[1];
  const float* bq = (const float*)d_in[2];
  const float* Wk = (const float*)d_in[3];
  const float* bk = (const float*)d_in[4];
  const float* Wv = (const float*)d_in[5];
  const float* bv = (const float*)d_in[6];
  const float* Wo = (const float*)d_in[7];
  const float* bo = (const float*)d_in[8];
  float* out = (float*)d_out;

  unsigned short* xb  = (unsigned short*)d_ws;               // 8192*1024
  unsigned short* btq = xb + (size_t)8192 * 1024;            // 3072*1024
  unsigned short* wot = btq + (size_t)3072 * 1024;           // 1024*1024
  unsigned short* qb  = wot + (size_t)1024 * 1024;           // 64*2048*64
  unsigned short* kb  = qb + (size_t)64 * 2048 * 64;
  unsigned short* vtb = kb + (size_t)64 * 2048 * 64;

  cast_x_kernel<<<8192, 256, 0, stream>>>((const float4*)x, xb);
  repack_wqkv<<<dim3(16, 16, 3), 256, 0, stream>>>(Wq, Wk, Wv, btq);
  repack_wo<<<dim3(16, 16), 256, 0, stream>>>(Wo, wot);

  // QKV: [8192,1024] x [1024,3072] -> q/k/vT (attn layouts; q pre-scaled)
  gemm_bt<0><<<dim3(64, 24), 256, 0, stream>>>(xb, btq, bq, bk, bv, qb, kb, vtb,
                                               nullptr, 1024, 3072);
  // attention: 16 qp (heavy first) x 64 bh
  attn_fwd<<<1024, 256, 0, stream>>>(qb, kb, vtb, xb);
  // O-proj: [8192,1024] x [1024,1024] -> f32 out
  gemm_bt<1><<<dim3(64, 8), 256, 0, stream>>>(xb, wot, bo, nullptr, nullptr,
                                              nullptr, nullptr, nullptr, out,
                                              1024, 1024);
}